// Round 2
// baseline (1139.201 us; speedup 1.0000x reference)
//
#include <hip/hip_runtime.h>
#include <hip/hip_bf16.h>

// ---------------------------------------------------------------------------
// RGCN (basis decomposition) x4 layers + pair-scoring head.
//   - CSR by dst built once per call (histogram -> scan -> fill), (src,etype)
//     packed into one u32 per edge.
//   - k_transform2: LDS-tiled mini-GEMM [64 nodes] x [DI -> 96 outputs]
//     (basis0 | basis1 | wself). Transposed weights in LDS (padded +4 floats
//     so 32-lane column reads are bank-conflict-free), x tile in LDS,
//     8 nodes x 3 outputs per thread, float4 ds reads, fully unrolled.
//   - k_aggregate: pull over in-edges (no atomics) + tanh in place.
//   - cat [N,128] f32 holds all four layer states (concat layout).
//   - Head: one wave per pair, 256-dim dot + sigmoid.
// ---------------------------------------------------------------------------

#define ETYPE_SHIFT 28
#define SRC_MASK 0x0FFFFFFFu

__global__ void k_count(const int* __restrict__ dst, int* __restrict__ deg, int E) {
    int e = blockIdx.x * 256 + threadIdx.x;
    if (e < E) atomicAdd(&deg[dst[e]], 1);
}

__global__ void k_scan_block(const int* __restrict__ deg, int* __restrict__ rowptr,
                             int* __restrict__ blockSums, int n) {
    int i = blockIdx.x * 256 + threadIdx.x;
    int v = (i < n) ? deg[i] : 0;
    int val = v;
    int lane = threadIdx.x & 63;
    int wid = threadIdx.x >> 6;
    for (int d = 1; d < 64; d <<= 1) {
        int t = __shfl_up(val, d, 64);
        if (lane >= d) val += t;
    }
    __shared__ int wsum[4];
    if (lane == 63) wsum[wid] = val;
    __syncthreads();
    int off = 0;
    for (int w = 0; w < wid; ++w) off += wsum[w];
    val += off;
    if (i < n) rowptr[i + 1] = val;
    if (threadIdx.x == 255) blockSums[blockIdx.x] = val;
}

__global__ void k_scan_sums(const int* __restrict__ blockSums,
                            int* __restrict__ blockOffsets, int nb) {
    __shared__ int lds[1024];
    int tid = threadIdx.x;
    int v = (tid < nb) ? blockSums[tid] : 0;
    lds[tid] = v;
    __syncthreads();
    for (int d = 1; d < 1024; d <<= 1) {
        int t = (tid >= d) ? lds[tid - d] : 0;
        __syncthreads();
        lds[tid] += t;
        __syncthreads();
    }
    if (tid < nb) blockOffsets[tid] = lds[tid] - v;  // exclusive
}

__global__ void k_scan_add(int* __restrict__ rowptr, int* __restrict__ cursor,
                           const int* __restrict__ blockOffsets, int n) {
    int i = blockIdx.x * 256 + threadIdx.x;
    if (i == 0) { rowptr[0] = 0; cursor[0] = 0; }
    if (i < n) {
        int v = rowptr[i + 1] + blockOffsets[blockIdx.x];
        rowptr[i + 1] = v;
        cursor[i + 1] = v;
    }
}

__global__ void k_fill(const int* __restrict__ src, const int* __restrict__ dst,
                       const int* __restrict__ etype, int* __restrict__ cursor,
                       unsigned int* __restrict__ epack, int E) {
    int e = blockIdx.x * 256 + threadIdx.x;
    if (e < E) {
        int d = dst[e];
        int pos = atomicAdd(&cursor[d], 1);
        epack[pos] = (unsigned int)src[e] | ((unsigned int)etype[e] << ETYPE_SHIFT);
    }
}

// LDS-tiled transform: hb[n, 0..63] = x@basis0 | x@basis1,
// selfout[n, o] = x@wself + bias (written into cat column block, stride 128).
// Block = 256 threads, 64 nodes; thread = (output col o, 8 nodes).
template<int DI>
__global__ __launch_bounds__(256) void k_transform2(
    const float* __restrict__ xin, int in_stride,
    const float* __restrict__ basis, const float* __restrict__ wself,
    const float* __restrict__ bias,
    float* __restrict__ hb, float* __restrict__ selfout, int n)
{
    constexpr int DIP = DI + 4;              // padded row (floats): stride%32==4
    __shared__ float bT[96 * DIP];           // transposed b0|b1|wself
    __shared__ float xs[64 * DI];
    const int t = threadIdx.x;

    // stage basis (2*DI*32 floats), transpose to bT[(b*32+o)][i]
    for (int f = t; f < 2 * DI * 32; f += 256) {
        int b = f / (DI * 32);
        int rem = f - b * DI * 32;
        int i = rem >> 5, o = rem & 31;
        bT[(b * 32 + o) * DIP + i] = basis[f];
    }
    // stage wself -> bT[(64+o)][i]
    for (int f = t; f < DI * 32; f += 256) {
        int i = f >> 5, o = f & 31;
        bT[(64 + o) * DIP + i] = wself[f];
    }

    const int node0 = blockIdx.x * 64;
    constexpr int R4 = DI / 4;
    for (int f = t; f < 64 * R4; f += 256) {
        int nloc = f / R4, i4 = f - nloc * R4;
        int node = node0 + nloc;
        float4 v = make_float4(0.f, 0.f, 0.f, 0.f);
        if (node < n) v = *(const float4*)(xin + (size_t)node * in_stride + i4 * 4);
        *(float4*)(xs + nloc * DI + i4 * 4) = v;
    }
    __syncthreads();

    const int o = t & 31, g = t >> 5;        // 8 groups x 8 nodes
    float a0[8], a1[8], asf[8];
#pragma unroll
    for (int nn = 0; nn < 8; ++nn) { a0[nn] = 0.f; a1[nn] = 0.f; asf[nn] = 0.f; }
    const float* b0p = bT + o * DIP;
    const float* b1p = bT + (32 + o) * DIP;
    const float* wsp = bT + (64 + o) * DIP;
    const float* xbase = xs + g * 8 * DI;

#pragma unroll
    for (int ic = 0; ic < DI / 4; ++ic) {
        const int i = ic * 4;
        float4 b0v = *(const float4*)(b0p + i);
        float4 b1v = *(const float4*)(b1p + i);
        float4 wsv = *(const float4*)(wsp + i);
#pragma unroll
        for (int nn = 0; nn < 8; ++nn) {
            float4 xv = *(const float4*)(xbase + nn * DI + i);
            a0[nn] = fmaf(xv.x, b0v.x, a0[nn]);
            a0[nn] = fmaf(xv.y, b0v.y, a0[nn]);
            a0[nn] = fmaf(xv.z, b0v.z, a0[nn]);
            a0[nn] = fmaf(xv.w, b0v.w, a0[nn]);
            a1[nn] = fmaf(xv.x, b1v.x, a1[nn]);
            a1[nn] = fmaf(xv.y, b1v.y, a1[nn]);
            a1[nn] = fmaf(xv.z, b1v.z, a1[nn]);
            a1[nn] = fmaf(xv.w, b1v.w, a1[nn]);
            asf[nn] = fmaf(xv.x, wsv.x, asf[nn]);
            asf[nn] = fmaf(xv.y, wsv.y, asf[nn]);
            asf[nn] = fmaf(xv.z, wsv.z, asf[nn]);
            asf[nn] = fmaf(xv.w, wsv.w, asf[nn]);
        }
    }

    const float bia = bias[o];
#pragma unroll
    for (int nn = 0; nn < 8; ++nn) {
        int node = node0 + g * 8 + nn;
        if (node < n) {
            hb[(size_t)node * 64 + o]        = a0[nn];
            hb[(size_t)node * 64 + 32 + o]   = a1[nn];
            selfout[(size_t)node * 128 + o]  = asf[nn] + bia;
        }
    }
}

// Pull aggregation + tanh, in place on cat columns.
__global__ void k_aggregate(const float* __restrict__ hb,
                            const unsigned int* __restrict__ epack,
                            const int* __restrict__ rowptr,
                            const float* __restrict__ comp,  // [8,2]
                            float* __restrict__ cat_l,       // cat + l*32, stride 128
                            int n) {
    __shared__ float c[16];
    if (threadIdx.x < 16) c[threadIdx.x] = comp[threadIdx.x];
    __syncthreads();
    int t = blockIdx.x * 256 + threadIdx.x;
    int node = t >> 5;
    int o = t & 31;
    if (node >= n) return;
    float acc = cat_l[(size_t)node * 128 + o];
    int k0 = rowptr[node], k1 = rowptr[node + 1];
    for (int k = k0; k < k1; ++k) {
        unsigned int p = epack[k];
        int s = (int)(p & SRC_MASK);
        int et = (int)(p >> ETYPE_SHIFT);
        acc = fmaf(c[et * 2 + 0], hb[(size_t)s * 64 + o], acc);
        acc = fmaf(c[et * 2 + 1], hb[(size_t)s * 64 + 32 + o], acc);
    }
    cat_l[(size_t)node * 128 + o] = tanhf(acc);
}

__global__ void k_head(const float* __restrict__ cat, const int* __restrict__ uidx,
                       const int* __restrict__ iidx, const float* __restrict__ w,
                       const float* __restrict__ b, float* __restrict__ out, int B) {
    int p = blockIdx.x;
    if (p >= B) return;
    int lane = threadIdx.x;  // 0..63
    const float* cu = cat + (size_t)uidx[p] * 128;
    const float* ci = cat + (size_t)iidx[p] * 128;
    float s = 0.f;
    s = fmaf(cu[lane], w[lane], s);
    s = fmaf(cu[lane + 64], w[lane + 64], s);
    s = fmaf(ci[lane], w[lane + 128], s);
    s = fmaf(ci[lane + 64], w[lane + 192], s);
    for (int d = 32; d > 0; d >>= 1) s += __shfl_down(s, d, 64);
    if (lane == 0) out[p] = 1.f / (1.f + expf(-(s + b[0])));
}

extern "C" void kernel_launch(void* const* d_in, const int* in_sizes, int n_in,
                              void* d_out, int out_size, void* d_ws, size_t ws_size,
                              hipStream_t stream) {
    const float* x      = (const float*)d_in[0];
    const int*   src    = (const int*)d_in[1];
    const int*   dst    = (const int*)d_in[2];
    const int*   etype  = (const int*)d_in[3];
    const int*   uidx   = (const int*)d_in[4];
    const int*   iidx   = (const int*)d_in[5];
    const float* lin1_w = (const float*)d_in[22];
    const float* lin1_b = (const float*)d_in[23];

    const int N = in_sizes[0] / 64;
    const int E = in_sizes[1];
    const int B = in_sizes[4];

    // workspace carve-out (256B aligned)
    char* p = (char*)d_ws;
    auto alloc = [&](size_t bytes) -> void* {
        void* r = (void*)p;
        p += (bytes + 255) & ~(size_t)255;
        return r;
    };
    float*        hb           = (float*)alloc((size_t)N * 64 * sizeof(float));
    float*        cat          = (float*)alloc((size_t)N * 128 * sizeof(float));
    int*          rowptr       = (int*)alloc((size_t)(N + 1) * sizeof(int));
    int*          cursor       = (int*)alloc((size_t)(N + 1) * sizeof(int));
    unsigned int* epack        = (unsigned int*)alloc((size_t)E * sizeof(unsigned int));
    int           nb           = (N + 255) / 256;
    int*          blockSums    = (int*)alloc((size_t)nb * sizeof(int));
    int*          blockOffsets = (int*)alloc((size_t)nb * sizeof(int));

    // ---- CSR build ----
    hipMemsetAsync(cursor, 0, (size_t)(N + 1) * sizeof(int), stream);
    k_count<<<(E + 255) / 256, 256, 0, stream>>>(dst, cursor, E);
    k_scan_block<<<nb, 256, 0, stream>>>(cursor, rowptr, blockSums, N);
    k_scan_sums<<<1, 1024, 0, stream>>>(blockSums, blockOffsets, nb);
    k_scan_add<<<nb, 256, 0, stream>>>(rowptr, cursor, blockOffsets, N);
    k_fill<<<(E + 255) / 256, 256, 0, stream>>>(src, dst, etype, cursor, epack, E);

    // ---- 4 RGCN layers ----
    int tr_grid = (N + 63) / 64;
    int node_grid = (N * 32 + 255) / 256;
    for (int l = 0; l < 4; ++l) {
        const float* xin   = (l == 0) ? x : (cat + (size_t)(l - 1) * 32);
        int in_stride      = (l == 0) ? 64 : 128;
        const float* basis = (const float*)d_in[6 + l * 4];
        const float* comp  = (const float*)d_in[7 + l * 4];
        const float* wself = (const float*)d_in[8 + l * 4];
        const float* bias  = (const float*)d_in[9 + l * 4];
        if (l == 0)
            k_transform2<64><<<tr_grid, 256, 0, stream>>>(xin, in_stride, basis, wself,
                                                          bias, hb, cat + (size_t)l * 32, N);
        else
            k_transform2<32><<<tr_grid, 256, 0, stream>>>(xin, in_stride, basis, wself,
                                                          bias, hb, cat + (size_t)l * 32, N);
        k_aggregate<<<node_grid, 256, 0, stream>>>(hb, epack, rowptr, comp,
                                                   cat + (size_t)l * 32, N);
    }

    // ---- head ----
    k_head<<<B, 64, 0, stream>>>(cat, uidx, iidx, lin1_w, lin1_b, (float*)d_out, B);
}

// Round 3
// 744.747 us; speedup vs baseline: 1.5296x; 1.5296x over previous
//
#include <hip/hip_runtime.h>
#include <hip/hip_bf16.h>

// ---------------------------------------------------------------------------
// RGCN (basis decomposition) x4 layers + pair-scoring head.
//   - CSR by dst built once per call (histogram -> scan -> fill), (src,etype)
//     packed into one u32 per edge.
//   - k_transform2: LDS-tiled mini-GEMM [64 nodes] x [DI -> 96 outputs]
//     (basis0 | basis1 | wself). Weights transposed into LDS with float4
//     chunk-XOR swizzle (bank-conflict-free-ish column reads); x tile linear
//     (reads are group-uniform broadcasts). 8 nodes x 3 outputs per thread,
//     #pragma unroll 2 to bound register pressure (256-VGPR spill in R2).
//   - k_aggregate: pull over in-edges (no atomics) + tanh in place.
//   - cat [N,128] f32 holds all four layer states (concat layout).
//   - Head: one wave per pair, 256-dim dot + sigmoid.
// ---------------------------------------------------------------------------

#define ETYPE_SHIFT 28
#define SRC_MASK 0x0FFFFFFFu

__global__ void k_count(const int* __restrict__ dst, int* __restrict__ deg, int E) {
    int e = blockIdx.x * 256 + threadIdx.x;
    if (e < E) atomicAdd(&deg[dst[e]], 1);
}

__global__ void k_scan_block(const int* __restrict__ deg, int* __restrict__ rowptr,
                             int* __restrict__ blockSums, int n) {
    int i = blockIdx.x * 256 + threadIdx.x;
    int v = (i < n) ? deg[i] : 0;
    int val = v;
    int lane = threadIdx.x & 63;
    int wid = threadIdx.x >> 6;
    for (int d = 1; d < 64; d <<= 1) {
        int t = __shfl_up(val, d, 64);
        if (lane >= d) val += t;
    }
    __shared__ int wsum[4];
    if (lane == 63) wsum[wid] = val;
    __syncthreads();
    int off = 0;
    for (int w = 0; w < wid; ++w) off += wsum[w];
    val += off;
    if (i < n) rowptr[i + 1] = val;
    if (threadIdx.x == 255) blockSums[blockIdx.x] = val;
}

__global__ void k_scan_sums(const int* __restrict__ blockSums,
                            int* __restrict__ blockOffsets, int nb) {
    __shared__ int lds[1024];
    int tid = threadIdx.x;
    int v = (tid < nb) ? blockSums[tid] : 0;
    lds[tid] = v;
    __syncthreads();
    for (int d = 1; d < 1024; d <<= 1) {
        int t = (tid >= d) ? lds[tid - d] : 0;
        __syncthreads();
        lds[tid] += t;
        __syncthreads();
    }
    if (tid < nb) blockOffsets[tid] = lds[tid] - v;  // exclusive
}

__global__ void k_scan_add(int* __restrict__ rowptr, int* __restrict__ cursor,
                           const int* __restrict__ blockOffsets, int n) {
    int i = blockIdx.x * 256 + threadIdx.x;
    if (i == 0) { rowptr[0] = 0; cursor[0] = 0; }
    if (i < n) {
        int v = rowptr[i + 1] + blockOffsets[blockIdx.x];
        rowptr[i + 1] = v;
        cursor[i + 1] = v;
    }
}

__global__ void k_fill(const int* __restrict__ src, const int* __restrict__ dst,
                       const int* __restrict__ etype, int* __restrict__ cursor,
                       unsigned int* __restrict__ epack, int E) {
    int e = blockIdx.x * 256 + threadIdx.x;
    if (e < E) {
        int d = dst[e];
        int pos = atomicAdd(&cursor[d], 1);
        epack[pos] = (unsigned int)src[e] | ((unsigned int)etype[e] << ETYPE_SHIFT);
    }
}

// LDS-tiled transform: hb[n, 0..63] = x@basis0 | x@basis1,
// selfout[n, o] = x@wself + bias (written into cat column block, stride 128).
// Block = 256 threads, 64 nodes; thread = (output col o = t&31, 8 nodes).
template<int DI>
__global__ __launch_bounds__(256) void k_transform2(
    const float* __restrict__ xin, int in_stride,
    const float* __restrict__ basis, const float* __restrict__ wself,
    const float* __restrict__ bias,
    float* __restrict__ hb, float* __restrict__ selfout, int n)
{
    constexpr int CH = DI / 4;                   // float4 chunks per row
    constexpr int CHM = (CH >= 16) ? 15 : 7;     // swizzle mask
    __shared__ float bT[96 * DI];                // rows: b0(o) | b1(32+o) | ws(64+o)
    __shared__ float xs[64 * DI];                // linear; reads are broadcasts
    const int t = threadIdx.x;
    const int o = t & 31;

    // ---- stage weights, transposed + chunk-swizzled ----
    // f -> (rr = f>>5 selects (b,c), o = f&31): global reads coalesced over o.
    for (int f = t; f < 32 * 3 * CH; f += 256) {
        int oo = f & 31;
        int rr = f >> 5;                 // [0, 3*CH)
        int b = rr / CH;                 // 0,1 = basis; 2 = wself
        int c = rr - b * CH;
        float4 v;
        const float* srcp = (b < 2) ? (basis + (size_t)b * DI * 32 + (size_t)(4 * c) * 32 + oo)
                                    : (wself + (size_t)(4 * c) * 32 + oo);
        v.x = srcp[0];
        v.y = srcp[32];
        v.z = srcp[64];
        v.w = srcp[96];
        int row = b * 32 + oo;
        *(float4*)(bT + (size_t)row * DI + 4 * (c ^ (oo & CHM))) = v;
    }

    // ---- stage x tile (linear) ----
    const int node0 = blockIdx.x * 64;
    for (int f = t; f < 64 * CH; f += 256) {
        int nloc = f / CH, i4 = f - nloc * CH;
        int node = node0 + nloc;
        float4 v = make_float4(0.f, 0.f, 0.f, 0.f);
        if (node < n) v = *(const float4*)(xin + (size_t)node * in_stride + i4 * 4);
        *(float4*)(xs + nloc * DI + i4 * 4) = v;
    }
    __syncthreads();

    const int g = t >> 5;                        // 8 groups x 8 nodes
    float a0[8], a1[8], asf[8];
#pragma unroll
    for (int nn = 0; nn < 8; ++nn) { a0[nn] = 0.f; a1[nn] = 0.f; asf[nn] = 0.f; }
    const float4* b0p = (const float4*)(bT + (size_t)o * DI);
    const float4* b1p = (const float4*)(bT + (size_t)(32 + o) * DI);
    const float4* wsp = (const float4*)(bT + (size_t)(64 + o) * DI);
    const float* xbase = xs + g * 8 * DI;
    const int sw = o & CHM;

#pragma unroll 2
    for (int ic = 0; ic < CH; ++ic) {
        const int c = ic ^ sw;
        float4 b0v = b0p[c];
        float4 b1v = b1p[c];
        float4 wsv = wsp[c];
#pragma unroll
        for (int nn = 0; nn < 8; ++nn) {
            float4 xv = *(const float4*)(xbase + nn * DI + ic * 4);
            a0[nn] = fmaf(xv.x, b0v.x, a0[nn]);
            a0[nn] = fmaf(xv.y, b0v.y, a0[nn]);
            a0[nn] = fmaf(xv.z, b0v.z, a0[nn]);
            a0[nn] = fmaf(xv.w, b0v.w, a0[nn]);
            a1[nn] = fmaf(xv.x, b1v.x, a1[nn]);
            a1[nn] = fmaf(xv.y, b1v.y, a1[nn]);
            a1[nn] = fmaf(xv.z, b1v.z, a1[nn]);
            a1[nn] = fmaf(xv.w, b1v.w, a1[nn]);
            asf[nn] = fmaf(xv.x, wsv.x, asf[nn]);
            asf[nn] = fmaf(xv.y, wsv.y, asf[nn]);
            asf[nn] = fmaf(xv.z, wsv.z, asf[nn]);
            asf[nn] = fmaf(xv.w, wsv.w, asf[nn]);
        }
    }

    const float bia = bias[o];
#pragma unroll
    for (int nn = 0; nn < 8; ++nn) {
        int node = node0 + g * 8 + nn;
        if (node < n) {
            hb[(size_t)node * 64 + o]        = a0[nn];
            hb[(size_t)node * 64 + 32 + o]   = a1[nn];
            selfout[(size_t)node * 128 + o]  = asf[nn] + bia;
        }
    }
}

// Pull aggregation + tanh, in place on cat columns.
__global__ void k_aggregate(const float* __restrict__ hb,
                            const unsigned int* __restrict__ epack,
                            const int* __restrict__ rowptr,
                            const float* __restrict__ comp,  // [8,2]
                            float* __restrict__ cat_l,       // cat + l*32, stride 128
                            int n) {
    __shared__ float c[16];
    if (threadIdx.x < 16) c[threadIdx.x] = comp[threadIdx.x];
    __syncthreads();
    int t = blockIdx.x * 256 + threadIdx.x;
    int node = t >> 5;
    int o = t & 31;
    if (node >= n) return;
    float acc = cat_l[(size_t)node * 128 + o];
    int k0 = rowptr[node], k1 = rowptr[node + 1];
    for (int k = k0; k < k1; ++k) {
        unsigned int p = epack[k];
        int s = (int)(p & SRC_MASK);
        int et = (int)(p >> ETYPE_SHIFT);
        acc = fmaf(c[et * 2 + 0], hb[(size_t)s * 64 + o], acc);
        acc = fmaf(c[et * 2 + 1], hb[(size_t)s * 64 + 32 + o], acc);
    }
    cat_l[(size_t)node * 128 + o] = tanhf(acc);
}

__global__ void k_head(const float* __restrict__ cat, const int* __restrict__ uidx,
                       const int* __restrict__ iidx, const float* __restrict__ w,
                       const float* __restrict__ b, float* __restrict__ out, int B) {
    int p = blockIdx.x;
    if (p >= B) return;
    int lane = threadIdx.x;  // 0..63
    const float* cu = cat + (size_t)uidx[p] * 128;
    const float* ci = cat + (size_t)iidx[p] * 128;
    float s = 0.f;
    s = fmaf(cu[lane], w[lane], s);
    s = fmaf(cu[lane + 64], w[lane + 64], s);
    s = fmaf(ci[lane], w[lane + 128], s);
    s = fmaf(ci[lane + 64], w[lane + 192], s);
    for (int d = 32; d > 0; d >>= 1) s += __shfl_down(s, d, 64);
    if (lane == 0) out[p] = 1.f / (1.f + expf(-(s + b[0])));
}

extern "C" void kernel_launch(void* const* d_in, const int* in_sizes, int n_in,
                              void* d_out, int out_size, void* d_ws, size_t ws_size,
                              hipStream_t stream) {
    const float* x      = (const float*)d_in[0];
    const int*   src    = (const int*)d_in[1];
    const int*   dst    = (const int*)d_in[2];
    const int*   etype  = (const int*)d_in[3];
    const int*   uidx   = (const int*)d_in[4];
    const int*   iidx   = (const int*)d_in[5];
    const float* lin1_w = (const float*)d_in[22];
    const float* lin1_b = (const float*)d_in[23];

    const int N = in_sizes[0] / 64;
    const int E = in_sizes[1];
    const int B = in_sizes[4];

    // workspace carve-out (256B aligned)
    char* p = (char*)d_ws;
    auto alloc = [&](size_t bytes) -> void* {
        void* r = (void*)p;
        p += (bytes + 255) & ~(size_t)255;
        return r;
    };
    float*        hb           = (float*)alloc((size_t)N * 64 * sizeof(float));
    float*        cat          = (float*)alloc((size_t)N * 128 * sizeof(float));
    int*          rowptr       = (int*)alloc((size_t)(N + 1) * sizeof(int));
    int*          cursor       = (int*)alloc((size_t)(N + 1) * sizeof(int));
    unsigned int* epack        = (unsigned int*)alloc((size_t)E * sizeof(unsigned int));
    int           nb           = (N + 255) / 256;
    int*          blockSums    = (int*)alloc((size_t)nb * sizeof(int));
    int*          blockOffsets = (int*)alloc((size_t)nb * sizeof(int));

    // ---- CSR build ----
    hipMemsetAsync(cursor, 0, (size_t)(N + 1) * sizeof(int), stream);
    k_count<<<(E + 255) / 256, 256, 0, stream>>>(dst, cursor, E);
    k_scan_block<<<nb, 256, 0, stream>>>(cursor, rowptr, blockSums, N);
    k_scan_sums<<<1, 1024, 0, stream>>>(blockSums, blockOffsets, nb);
    k_scan_add<<<nb, 256, 0, stream>>>(rowptr, cursor, blockOffsets, N);
    k_fill<<<(E + 255) / 256, 256, 0, stream>>>(src, dst, etype, cursor, epack, E);

    // ---- 4 RGCN layers ----
    int tr_grid = (N + 63) / 64;
    int node_grid = (N * 32 + 255) / 256;
    for (int l = 0; l < 4; ++l) {
        const float* xin   = (l == 0) ? x : (cat + (size_t)(l - 1) * 32);
        int in_stride      = (l == 0) ? 64 : 128;
        const float* basis = (const float*)d_in[6 + l * 4];
        const float* comp  = (const float*)d_in[7 + l * 4];
        const float* wself = (const float*)d_in[8 + l * 4];
        const float* bias  = (const float*)d_in[9 + l * 4];
        if (l == 0)
            k_transform2<64><<<tr_grid, 256, 0, stream>>>(xin, in_stride, basis, wself,
                                                          bias, hb, cat + (size_t)l * 32, N);
        else
            k_transform2<32><<<tr_grid, 256, 0, stream>>>(xin, in_stride, basis, wself,
                                                          bias, hb, cat + (size_t)l * 32, N);
        k_aggregate<<<node_grid, 256, 0, stream>>>(hb, epack, rowptr, comp,
                                                   cat + (size_t)l * 32, N);
    }

    // ---- head ----
    k_head<<<B, 64, 0, stream>>>(cat, uidx, iidx, lin1_w, lin1_b, (float*)d_out, B);
}

// Round 4
// 607.325 us; speedup vs baseline: 1.8758x; 1.2263x over previous
//
#include <hip/hip_runtime.h>
#include <hip/hip_bf16.h>

// ---------------------------------------------------------------------------
// RGCN (basis decomposition) x4 layers + pair-scoring head.
//
// CSR build (bucket pipeline, replaces count/scan/fill with random atomics):
//   A  k_buk_count      : LDS histogram of dst>>9 (512-node buckets)
//   A2 k_buk_scan       : 1-block exclusive scan -> bukOff[0..NBUK]
//   B  k_binscatter     : per 2048-edge block: counting-sort into LDS by
//                         bucket, reserve global space per bucket, write
//                         contiguous segments (kills 16x write amplification)
//   C  k_bucket_finalize: per bucket: node histogram + scan in LDS, writes
//                         rowptr coalesced, scatters epack into a 16KB window
//
// Layers:
//   k_transform2 : LDS-tiled mini-GEMM -> hb2 (bf16x2 packed: both bases for
//                  output o in one u32 => aggregate reads ONE 128B line/edge)
//                  + self part into cat (f32).
//   k_aggregate  : pull over in-edges (no atomics) + tanh in place.
//   cat [N,128] f32 holds all four layer states (concat layout).
//   k_head       : one wave per pair, 256-dim dot + sigmoid.
// ---------------------------------------------------------------------------

#define ETYPE_SHIFT 28
#define SRC_MASK 0x0FFFFFFFu
#define BUK_SH 9
#define BUK_W 512

__device__ inline unsigned int f2bf(float f) {
    unsigned int u = __float_as_uint(f);
    return (u + 0x7FFFu + ((u >> 16) & 1u)) >> 16;
}

// Exclusive scan in place of a[0..M), M%4==0, M/4 <= 256. 256-thread block.
__device__ inline void block_exscan(int* a, int M, int* wsum /*shared int[4]*/) {
    const int t = threadIdx.x;
    const int q = M >> 2;
    int s0 = 0, s1 = 0, s2 = 0, s3 = 0, s = 0;
    if (t < q) {
        s0 = a[4 * t]; s1 = a[4 * t + 1]; s2 = a[4 * t + 2]; s3 = a[4 * t + 3];
        s = s0 + s1 + s2 + s3;
    }
    int lane = t & 63, wid = t >> 6;
    int val = s;
    for (int d = 1; d < 64; d <<= 1) {
        int u = __shfl_up(val, d, 64);
        if (lane >= d) val += u;
    }
    if (lane == 63) wsum[wid] = val;
    __syncthreads();
    int woff = 0;
    for (int w = 0; w < wid; ++w) woff += wsum[w];
    val += woff;              // inclusive over block
    int base = val - s;       // exclusive base for this thread's 4 elems
    __syncthreads();
    if (t < q) {
        a[4 * t]     = base;
        a[4 * t + 1] = base + s0;
        a[4 * t + 2] = base + s0 + s1;
        a[4 * t + 3] = base + s0 + s1 + s2;
    }
    __syncthreads();
}

// ---- A: bucket histogram ----
__global__ __launch_bounds__(256) void k_buk_count(const int* __restrict__ dst,
                                                   int* __restrict__ gBukCnt, int E) {
    __shared__ int hist[1024];
    const int t = threadIdx.x;
    for (int f = t; f < 1024; f += 256) hist[f] = 0;
    __syncthreads();
    int e0 = blockIdx.x * 2048;
    for (int k = 0; k < 8; ++k) {
        int e = e0 + k * 256 + t;
        if (e < E) atomicAdd(&hist[dst[e] >> BUK_SH], 1);
    }
    __syncthreads();
    for (int f = t; f < 1024; f += 256) {
        int c = hist[f];
        if (c) atomicAdd(&gBukCnt[f], c);
    }
}

// ---- A2: scan bucket counts (1 block, 1024 threads; nb <= 1024) ----
__global__ void k_buk_scan(const int* __restrict__ gBukCnt, int* __restrict__ bukOff,
                           int nb) {
    __shared__ int lds[1024];
    int tid = threadIdx.x;
    int v = (tid < nb) ? gBukCnt[tid] : 0;
    lds[tid] = v;
    __syncthreads();
    for (int d = 1; d < 1024; d <<= 1) {
        int u = (tid >= d) ? lds[tid - d] : 0;
        __syncthreads();
        lds[tid] += u;
        __syncthreads();
    }
    if (tid < nb) bukOff[tid] = lds[tid] - v;       // exclusive
    if (tid == nb - 1) bukOff[nb] = lds[tid];       // total = E
}

// ---- B: block counting-sort by bucket + contiguous segment writeout ----
__global__ __launch_bounds__(256) void k_binscatter(
    const int* __restrict__ src, const int* __restrict__ dst,
    const int* __restrict__ etype, const int* __restrict__ bukOff,
    int* __restrict__ gBukCur, unsigned long long* __restrict__ binned,
    int E, int NBUK)
{
    __shared__ int hist[1024];
    __shared__ int offs[1024];
    __shared__ int cur[1024];
    __shared__ int gb[1024];
    __shared__ int wsum[4];
    __shared__ unsigned long long stage[2048];
    const int t = threadIdx.x;
    for (int f = t; f < 1024; f += 256) { hist[f] = 0; cur[f] = 0; }
    __syncthreads();

    const int e0 = blockIdx.x * 2048;
    const int cntTot = min(2048, E - e0);
    unsigned long long pk[8];
    int bk[8];
#pragma unroll
    for (int k = 0; k < 8; ++k) {
        int e = e0 + k * 256 + t;
        if (e < E) {
            int d = dst[e];
            bk[k] = d >> BUK_SH;
            pk[k] = ((unsigned long long)(unsigned int)d << 32)
                  | (unsigned int)(src[e] | (etype[e] << ETYPE_SHIFT));
            atomicAdd(&hist[bk[k]], 1);
        } else bk[k] = -1;
    }
    __syncthreads();
    for (int f = t; f < 1024; f += 256) offs[f] = hist[f];
    __syncthreads();
    block_exscan(offs, 1024, wsum);
#pragma unroll
    for (int k = 0; k < 8; ++k) {
        if (bk[k] >= 0) {
            int pos = offs[bk[k]] + atomicAdd(&cur[bk[k]], 1);
            stage[pos] = pk[k];
        }
    }
    // reserve global space per bucket (one atomic per non-empty bucket)
    for (int f = t; f < NBUK; f += 256) {
        int c = hist[f];
        if (c > 0) gb[f] = bukOff[f] + atomicAdd(&gBukCur[f], c);
    }
    __syncthreads();
    // contiguous per-bucket segments
    for (int k = t; k < cntTot; k += 256) {
        unsigned long long v = stage[k];
        int b = (int)((unsigned int)(v >> 32) >> BUK_SH);
        binned[(size_t)gb[b] + (size_t)(k - offs[b])] = v;
    }
}

// ---- C: per-bucket finalize: rowptr + epack (all writes in 16KB window) ----
__global__ __launch_bounds__(256) void k_bucket_finalize(
    const unsigned long long* __restrict__ binned, const int* __restrict__ bukOff,
    int* __restrict__ rowptr, unsigned int* __restrict__ epack, int N, int E)
{
    __shared__ int nhist[512];
    __shared__ int ncur[512];
    __shared__ int wsum[4];
    const int t = threadIdx.x;
    const int b = blockIdx.x;
    for (int f = t; f < 512; f += 256) { nhist[f] = 0; ncur[f] = 0; }
    __syncthreads();
    const int k0 = bukOff[b], k1 = bukOff[b + 1];
    for (int k = k0 + t; k < k1; k += 256)
        atomicAdd(&nhist[(int)((unsigned int)(binned[k] >> 32) & (BUK_W - 1))], 1);
    __syncthreads();
    block_exscan(nhist, 512, wsum);
    for (int f = t; f < 512; f += 256) {
        int node = (b << BUK_SH) + f;
        if (node < N) rowptr[node] = k0 + nhist[f];
    }
    if (b == 0 && t == 0) rowptr[N] = E;
    for (int k = k0 + t; k < k1; k += 256) {
        unsigned long long v = binned[k];
        int dl = (int)((unsigned int)(v >> 32) & (BUK_W - 1));
        int pos = k0 + nhist[dl] + atomicAdd(&ncur[dl], 1);
        epack[pos] = (unsigned int)v;
    }
}

// LDS-tiled transform: hb2[n,o] = pack_bf16(x@basis0, x@basis1),
// selfout[n,o] = x@wself + bias (into cat column block, stride 128).
template<int DI>
__global__ __launch_bounds__(256) void k_transform2(
    const float* __restrict__ xin, int in_stride,
    const float* __restrict__ basis, const float* __restrict__ wself,
    const float* __restrict__ bias,
    unsigned int* __restrict__ hb2, float* __restrict__ selfout, int n)
{
    constexpr int CH = DI / 4;
    constexpr int CHM = (CH >= 16) ? 15 : 7;
    __shared__ float bT[96 * DI];
    __shared__ float xs[64 * DI];
    const int t = threadIdx.x;
    const int o = t & 31;

    for (int f = t; f < 32 * 3 * CH; f += 256) {
        int oo = f & 31;
        int rr = f >> 5;
        int b = rr / CH;
        int c = rr - b * CH;
        float4 v;
        const float* srcp = (b < 2) ? (basis + (size_t)b * DI * 32 + (size_t)(4 * c) * 32 + oo)
                                    : (wself + (size_t)(4 * c) * 32 + oo);
        v.x = srcp[0];
        v.y = srcp[32];
        v.z = srcp[64];
        v.w = srcp[96];
        int row = b * 32 + oo;
        *(float4*)(bT + (size_t)row * DI + 4 * (c ^ (oo & CHM))) = v;
    }

    const int node0 = blockIdx.x * 64;
    for (int f = t; f < 64 * CH; f += 256) {
        int nloc = f / CH, i4 = f - nloc * CH;
        int node = node0 + nloc;
        float4 v = make_float4(0.f, 0.f, 0.f, 0.f);
        if (node < n) v = *(const float4*)(xin + (size_t)node * in_stride + i4 * 4);
        *(float4*)(xs + nloc * DI + i4 * 4) = v;
    }
    __syncthreads();

    const int g = t >> 5;
    float a0[8], a1[8], asf[8];
#pragma unroll
    for (int nn = 0; nn < 8; ++nn) { a0[nn] = 0.f; a1[nn] = 0.f; asf[nn] = 0.f; }
    const float4* b0p = (const float4*)(bT + (size_t)o * DI);
    const float4* b1p = (const float4*)(bT + (size_t)(32 + o) * DI);
    const float4* wsp = (const float4*)(bT + (size_t)(64 + o) * DI);
    const float* xbase = xs + g * 8 * DI;
    const int sw = o & CHM;

#pragma unroll 2
    for (int ic = 0; ic < CH; ++ic) {
        const int c = ic ^ sw;
        float4 b0v = b0p[c];
        float4 b1v = b1p[c];
        float4 wsv = wsp[c];
#pragma unroll
        for (int nn = 0; nn < 8; ++nn) {
            float4 xv = *(const float4*)(xbase + nn * DI + ic * 4);
            a0[nn] = fmaf(xv.x, b0v.x, a0[nn]);
            a0[nn] = fmaf(xv.y, b0v.y, a0[nn]);
            a0[nn] = fmaf(xv.z, b0v.z, a0[nn]);
            a0[nn] = fmaf(xv.w, b0v.w, a0[nn]);
            a1[nn] = fmaf(xv.x, b1v.x, a1[nn]);
            a1[nn] = fmaf(xv.y, b1v.y, a1[nn]);
            a1[nn] = fmaf(xv.z, b1v.z, a1[nn]);
            a1[nn] = fmaf(xv.w, b1v.w, a1[nn]);
            asf[nn] = fmaf(xv.x, wsv.x, asf[nn]);
            asf[nn] = fmaf(xv.y, wsv.y, asf[nn]);
            asf[nn] = fmaf(xv.z, wsv.z, asf[nn]);
            asf[nn] = fmaf(xv.w, wsv.w, asf[nn]);
        }
    }

    const float bia = bias[o];
#pragma unroll
    for (int nn = 0; nn < 8; ++nn) {
        int node = node0 + g * 8 + nn;
        if (node < n) {
            hb2[(size_t)node * 32 + o]      = f2bf(a0[nn]) | (f2bf(a1[nn]) << 16);
            selfout[(size_t)node * 128 + o] = asf[nn] + bia;
        }
    }
}

// Pull aggregation + tanh, in place on cat columns. One 128B line per edge.
__global__ void k_aggregate(const unsigned int* __restrict__ hb2,
                            const unsigned int* __restrict__ epack,
                            const int* __restrict__ rowptr,
                            const float* __restrict__ comp,  // [8,2]
                            float* __restrict__ cat_l,       // cat + l*32, stride 128
                            int n) {
    __shared__ float c[16];
    if (threadIdx.x < 16) c[threadIdx.x] = comp[threadIdx.x];
    __syncthreads();
    int t = blockIdx.x * 256 + threadIdx.x;
    int node = t >> 5;
    int o = t & 31;
    if (node >= n) return;
    float acc = cat_l[(size_t)node * 128 + o];
    int k0 = rowptr[node], k1 = rowptr[node + 1];
    for (int k = k0; k < k1; ++k) {
        unsigned int p = epack[k];
        int s = (int)(p & SRC_MASK);
        int et = (int)(p >> ETYPE_SHIFT);
        unsigned int h = hb2[(size_t)s * 32 + o];
        float h0 = __uint_as_float((h & 0xFFFFu) << 16);
        float h1 = __uint_as_float(h & 0xFFFF0000u);
        acc = fmaf(c[et * 2 + 0], h0, acc);
        acc = fmaf(c[et * 2 + 1], h1, acc);
    }
    cat_l[(size_t)node * 128 + o] = tanhf(acc);
}

__global__ void k_head(const float* __restrict__ cat, const int* __restrict__ uidx,
                       const int* __restrict__ iidx, const float* __restrict__ w,
                       const float* __restrict__ b, float* __restrict__ out, int B) {
    int p = blockIdx.x;
    if (p >= B) return;
    int lane = threadIdx.x;  // 0..63
    const float* cu = cat + (size_t)uidx[p] * 128;
    const float* ci = cat + (size_t)iidx[p] * 128;
    float s = 0.f;
    s = fmaf(cu[lane], w[lane], s);
    s = fmaf(cu[lane + 64], w[lane + 64], s);
    s = fmaf(ci[lane], w[lane + 128], s);
    s = fmaf(ci[lane + 64], w[lane + 192], s);
    for (int d = 32; d > 0; d >>= 1) s += __shfl_down(s, d, 64);
    if (lane == 0) out[p] = 1.f / (1.f + expf(-(s + b[0])));
}

extern "C" void kernel_launch(void* const* d_in, const int* in_sizes, int n_in,
                              void* d_out, int out_size, void* d_ws, size_t ws_size,
                              hipStream_t stream) {
    const float* x      = (const float*)d_in[0];
    const int*   src    = (const int*)d_in[1];
    const int*   dst    = (const int*)d_in[2];
    const int*   etype  = (const int*)d_in[3];
    const int*   uidx   = (const int*)d_in[4];
    const int*   iidx   = (const int*)d_in[5];
    const float* lin1_w = (const float*)d_in[22];
    const float* lin1_b = (const float*)d_in[23];

    const int N = in_sizes[0] / 64;
    const int E = in_sizes[1];
    const int B = in_sizes[4];
    const int NBUK = (N + BUK_W - 1) >> BUK_SH;

    // workspace carve-out (256B aligned)
    char* p = (char*)d_ws;
    auto alloc = [&](size_t bytes) -> void* {
        void* r = (void*)p;
        p += (bytes + 255) & ~(size_t)255;
        return r;
    };
    unsigned int*       hb2     = (unsigned int*)alloc((size_t)N * 32 * sizeof(unsigned int));
    float*              cat     = (float*)alloc((size_t)N * 128 * sizeof(float));
    int*                rowptr  = (int*)alloc((size_t)(N + 1) * sizeof(int));
    unsigned int*       epack   = (unsigned int*)alloc((size_t)E * sizeof(unsigned int));
    unsigned long long* binned  = (unsigned long long*)alloc((size_t)E * sizeof(unsigned long long));
    int*                gBukCnt = (int*)alloc(1024 * sizeof(int));
    int*                gBukCur = (int*)alloc(1024 * sizeof(int));  // adjacent to gBukCnt
    int*                bukOff  = (int*)alloc(1025 * sizeof(int));

    // ---- CSR build (bucket pipeline) ----
    hipMemsetAsync(gBukCnt, 0, 2048 * sizeof(int), stream);  // gBukCnt + gBukCur
    int ebGrid = (E + 2047) / 2048;
    k_buk_count<<<ebGrid, 256, 0, stream>>>(dst, gBukCnt, E);
    k_buk_scan<<<1, 1024, 0, stream>>>(gBukCnt, bukOff, NBUK);
    k_binscatter<<<ebGrid, 256, 0, stream>>>(src, dst, etype, bukOff, gBukCur,
                                             binned, E, NBUK);
    k_bucket_finalize<<<NBUK, 256, 0, stream>>>(binned, bukOff, rowptr, epack, N, E);

    // ---- 4 RGCN layers ----
    int tr_grid = (N + 63) / 64;
    int node_grid = (N * 32 + 255) / 256;
    for (int l = 0; l < 4; ++l) {
        const float* xin   = (l == 0) ? x : (cat + (size_t)(l - 1) * 32);
        int in_stride      = (l == 0) ? 64 : 128;
        const float* basis = (const float*)d_in[6 + l * 4];
        const float* comp  = (const float*)d_in[7 + l * 4];
        const float* wself = (const float*)d_in[8 + l * 4];
        const float* bias  = (const float*)d_in[9 + l * 4];
        if (l == 0)
            k_transform2<64><<<tr_grid, 256, 0, stream>>>(xin, in_stride, basis, wself,
                                                          bias, hb2, cat + (size_t)l * 32, N);
        else
            k_transform2<32><<<tr_grid, 256, 0, stream>>>(xin, in_stride, basis, wself,
                                                          bias, hb2, cat + (size_t)l * 32, N);
        k_aggregate<<<node_grid, 256, 0, stream>>>(hb2, epack, rowptr, comp,
                                                   cat + (size_t)l * 32, N);
    }

    // ---- head ----
    k_head<<<B, 64, 0, stream>>>(cat, uidx, iidx, lin1_w, lin1_b, (float*)d_out, B);
}

// Round 5
// 386.948 us; speedup vs baseline: 2.9441x; 1.5695x over previous
//
#include <hip/hip_runtime.h>
#include <hip/hip_bf16.h>

// ---------------------------------------------------------------------------
// RGCN (basis decomposition) x4 layers + pair-scoring head.
//
// CSR build (bucket pipeline):
//   A  k_buk_count      : LDS histogram of dst>>9 (512-node buckets)
//   A2 k_buk_scan       : 1-block exclusive scan -> bukOff[0..NBUK]
//   B  k_binscatter     : per 2048-edge block: counting-sort into LDS by
//                         bucket, reserve global space, contiguous writeout
//   C  k_bucket_finalize: per bucket: node histogram + scan in LDS, writes
//                         rowptr coalesced, scatters epack into 16KB window
//
// Layers:
//   k_transform2 : LDS-tiled mini-GEMM -> hb2 (bf16x2: both bases per output
//                  in one u32 -> ONE 128B line per edge gather) + self into cat
//   k_aggregate  : pull over in-edges, masked 8-wide software pipeline
//                  (8 gathers in flight per thread -> latency hiding), tanh.
//   cat [N,128] f32 holds all four layer states (concat layout).
//   k_head       : one wave per pair, 256-dim dot + sigmoid.
// ---------------------------------------------------------------------------

#define ETYPE_SHIFT 28
#define SRC_MASK 0x0FFFFFFFu
#define BUK_SH 9
#define BUK_W 512

__device__ inline unsigned int f2bf(float f) {
    unsigned int u = __float_as_uint(f);
    return (u + 0x7FFFu + ((u >> 16) & 1u)) >> 16;
}

// Exclusive scan in place of a[0..M), M%4==0, M/4 <= 256. 256-thread block.
__device__ inline void block_exscan(int* a, int M, int* wsum /*shared int[4]*/) {
    const int t = threadIdx.x;
    const int q = M >> 2;
    int s0 = 0, s1 = 0, s2 = 0, s3 = 0, s = 0;
    if (t < q) {
        s0 = a[4 * t]; s1 = a[4 * t + 1]; s2 = a[4 * t + 2]; s3 = a[4 * t + 3];
        s = s0 + s1 + s2 + s3;
    }
    int lane = t & 63, wid = t >> 6;
    int val = s;
    for (int d = 1; d < 64; d <<= 1) {
        int u = __shfl_up(val, d, 64);
        if (lane >= d) val += u;
    }
    if (lane == 63) wsum[wid] = val;
    __syncthreads();
    int woff = 0;
    for (int w = 0; w < wid; ++w) woff += wsum[w];
    val += woff;              // inclusive over block
    int base = val - s;       // exclusive base for this thread's 4 elems
    __syncthreads();
    if (t < q) {
        a[4 * t]     = base;
        a[4 * t + 1] = base + s0;
        a[4 * t + 2] = base + s0 + s1;
        a[4 * t + 3] = base + s0 + s1 + s2;
    }
    __syncthreads();
}

// ---- A: bucket histogram ----
__global__ __launch_bounds__(256) void k_buk_count(const int* __restrict__ dst,
                                                   int* __restrict__ gBukCnt, int E) {
    __shared__ int hist[1024];
    const int t = threadIdx.x;
    for (int f = t; f < 1024; f += 256) hist[f] = 0;
    __syncthreads();
    int e0 = blockIdx.x * 2048;
    for (int k = 0; k < 8; ++k) {
        int e = e0 + k * 256 + t;
        if (e < E) atomicAdd(&hist[dst[e] >> BUK_SH], 1);
    }
    __syncthreads();
    for (int f = t; f < 1024; f += 256) {
        int c = hist[f];
        if (c) atomicAdd(&gBukCnt[f], c);
    }
}

// ---- A2: scan bucket counts (1 block, 1024 threads; nb <= 1024) ----
__global__ void k_buk_scan(const int* __restrict__ gBukCnt, int* __restrict__ bukOff,
                           int nb) {
    __shared__ int lds[1024];
    int tid = threadIdx.x;
    int v = (tid < nb) ? gBukCnt[tid] : 0;
    lds[tid] = v;
    __syncthreads();
    for (int d = 1; d < 1024; d <<= 1) {
        int u = (tid >= d) ? lds[tid - d] : 0;
        __syncthreads();
        lds[tid] += u;
        __syncthreads();
    }
    if (tid < nb) bukOff[tid] = lds[tid] - v;       // exclusive
    if (tid == nb - 1) bukOff[nb] = lds[tid];       // total = E
}

// ---- B: block counting-sort by bucket + contiguous segment writeout ----
__global__ __launch_bounds__(256) void k_binscatter(
    const int* __restrict__ src, const int* __restrict__ dst,
    const int* __restrict__ etype, const int* __restrict__ bukOff,
    int* __restrict__ gBukCur, unsigned long long* __restrict__ binned,
    int E, int NBUK)
{
    __shared__ int hist[1024];
    __shared__ int offs[1024];
    __shared__ int cur[1024];
    __shared__ int gb[1024];
    __shared__ int wsum[4];
    __shared__ unsigned long long stage[2048];
    const int t = threadIdx.x;
    for (int f = t; f < 1024; f += 256) { hist[f] = 0; cur[f] = 0; }
    __syncthreads();

    const int e0 = blockIdx.x * 2048;
    const int cntTot = min(2048, E - e0);
    unsigned long long pk[8];
    int bk[8];
#pragma unroll
    for (int k = 0; k < 8; ++k) {
        int e = e0 + k * 256 + t;
        if (e < E) {
            int d = dst[e];
            bk[k] = d >> BUK_SH;
            pk[k] = ((unsigned long long)(unsigned int)d << 32)
                  | (unsigned int)(src[e] | (etype[e] << ETYPE_SHIFT));
            atomicAdd(&hist[bk[k]], 1);
        } else bk[k] = -1;
    }
    __syncthreads();
    for (int f = t; f < 1024; f += 256) offs[f] = hist[f];
    __syncthreads();
    block_exscan(offs, 1024, wsum);
#pragma unroll
    for (int k = 0; k < 8; ++k) {
        if (bk[k] >= 0) {
            int pos = offs[bk[k]] + atomicAdd(&cur[bk[k]], 1);
            stage[pos] = pk[k];
        }
    }
    // reserve global space per bucket (one atomic per non-empty bucket)
    for (int f = t; f < NBUK; f += 256) {
        int c = hist[f];
        if (c > 0) gb[f] = bukOff[f] + atomicAdd(&gBukCur[f], c);
    }
    __syncthreads();
    // contiguous per-bucket segments
    for (int k = t; k < cntTot; k += 256) {
        unsigned long long v = stage[k];
        int b = (int)((unsigned int)(v >> 32) >> BUK_SH);
        binned[(size_t)gb[b] + (size_t)(k - offs[b])] = v;
    }
}

// ---- C: per-bucket finalize: rowptr + epack (all writes in 16KB window) ----
__global__ __launch_bounds__(256) void k_bucket_finalize(
    const unsigned long long* __restrict__ binned, const int* __restrict__ bukOff,
    int* __restrict__ rowptr, unsigned int* __restrict__ epack, int N, int E)
{
    __shared__ int nhist[512];
    __shared__ int ncur[512];
    __shared__ int wsum[4];
    const int t = threadIdx.x;
    const int b = blockIdx.x;
    for (int f = t; f < 512; f += 256) { nhist[f] = 0; ncur[f] = 0; }
    __syncthreads();
    const int k0 = bukOff[b], k1 = bukOff[b + 1];
    for (int k = k0 + t; k < k1; k += 256)
        atomicAdd(&nhist[(int)((unsigned int)(binned[k] >> 32) & (BUK_W - 1))], 1);
    __syncthreads();
    block_exscan(nhist, 512, wsum);
    for (int f = t; f < 512; f += 256) {
        int node = (b << BUK_SH) + f;
        if (node < N) rowptr[node] = k0 + nhist[f];
    }
    if (b == 0 && t == 0) rowptr[N] = E;
    for (int k = k0 + t; k < k1; k += 256) {
        unsigned long long v = binned[k];
        int dl = (int)((unsigned int)(v >> 32) & (BUK_W - 1));
        int pos = k0 + nhist[dl] + atomicAdd(&ncur[dl], 1);
        epack[pos] = (unsigned int)v;
    }
}

// LDS-tiled transform: hb2[n,o] = pack_bf16(x@basis0, x@basis1),
// selfout[n,o] = x@wself + bias (into cat column block, stride 128).
template<int DI>
__global__ __launch_bounds__(256) void k_transform2(
    const float* __restrict__ xin, int in_stride,
    const float* __restrict__ basis, const float* __restrict__ wself,
    const float* __restrict__ bias,
    unsigned int* __restrict__ hb2, float* __restrict__ selfout, int n)
{
    constexpr int CH = DI / 4;
    constexpr int CHM = (CH >= 16) ? 15 : 7;
    __shared__ float bT[96 * DI];
    __shared__ float xs[64 * DI];
    const int t = threadIdx.x;
    const int o = t & 31;

    for (int f = t; f < 32 * 3 * CH; f += 256) {
        int oo = f & 31;
        int rr = f >> 5;
        int b = rr / CH;
        int c = rr - b * CH;
        float4 v;
        const float* srcp = (b < 2) ? (basis + (size_t)b * DI * 32 + (size_t)(4 * c) * 32 + oo)
                                    : (wself + (size_t)(4 * c) * 32 + oo);
        v.x = srcp[0];
        v.y = srcp[32];
        v.z = srcp[64];
        v.w = srcp[96];
        int row = b * 32 + oo;
        *(float4*)(bT + (size_t)row * DI + 4 * (c ^ (oo & CHM))) = v;
    }

    const int node0 = blockIdx.x * 64;
    for (int f = t; f < 64 * CH; f += 256) {
        int nloc = f / CH, i4 = f - nloc * CH;
        int node = node0 + nloc;
        float4 v = make_float4(0.f, 0.f, 0.f, 0.f);
        if (node < n) v = *(const float4*)(xin + (size_t)node * in_stride + i4 * 4);
        *(float4*)(xs + nloc * DI + i4 * 4) = v;
    }
    __syncthreads();

    const int g = t >> 5;
    float a0[8], a1[8], asf[8];
#pragma unroll
    for (int nn = 0; nn < 8; ++nn) { a0[nn] = 0.f; a1[nn] = 0.f; asf[nn] = 0.f; }
    const float4* b0p = (const float4*)(bT + (size_t)o * DI);
    const float4* b1p = (const float4*)(bT + (size_t)(32 + o) * DI);
    const float4* wsp = (const float4*)(bT + (size_t)(64 + o) * DI);
    const float* xbase = xs + g * 8 * DI;
    const int sw = o & CHM;

#pragma unroll 2
    for (int ic = 0; ic < CH; ++ic) {
        const int c = ic ^ sw;
        float4 b0v = b0p[c];
        float4 b1v = b1p[c];
        float4 wsv = wsp[c];
#pragma unroll
        for (int nn = 0; nn < 8; ++nn) {
            float4 xv = *(const float4*)(xbase + nn * DI + ic * 4);
            a0[nn] = fmaf(xv.x, b0v.x, a0[nn]);
            a0[nn] = fmaf(xv.y, b0v.y, a0[nn]);
            a0[nn] = fmaf(xv.z, b0v.z, a0[nn]);
            a0[nn] = fmaf(xv.w, b0v.w, a0[nn]);
            a1[nn] = fmaf(xv.x, b1v.x, a1[nn]);
            a1[nn] = fmaf(xv.y, b1v.y, a1[nn]);
            a1[nn] = fmaf(xv.z, b1v.z, a1[nn]);
            a1[nn] = fmaf(xv.w, b1v.w, a1[nn]);
            asf[nn] = fmaf(xv.x, wsv.x, asf[nn]);
            asf[nn] = fmaf(xv.y, wsv.y, asf[nn]);
            asf[nn] = fmaf(xv.z, wsv.z, asf[nn]);
            asf[nn] = fmaf(xv.w, wsv.w, asf[nn]);
        }
    }

    const float bia = bias[o];
#pragma unroll
    for (int nn = 0; nn < 8; ++nn) {
        int node = node0 + g * 8 + nn;
        if (node < n) {
            hb2[(size_t)node * 32 + o]      = f2bf(a0[nn]) | (f2bf(a1[nn]) << 16);
            selfout[(size_t)node * 128 + o] = asf[nn] + bia;
        }
    }
}

// Pull aggregation + tanh. Masked 8-wide software pipeline: all 8 epack loads
// then all 8 hb2 gathers issued back-to-back (8 lines in flight per thread).
__global__ void k_aggregate(const unsigned int* __restrict__ hb2,
                            const unsigned int* __restrict__ epack,
                            const int* __restrict__ rowptr,
                            const float* __restrict__ comp,  // [8,2]
                            float* __restrict__ cat_l,       // cat + l*32, stride 128
                            int n) {
    __shared__ float c[16];
    if (threadIdx.x < 16) c[threadIdx.x] = comp[threadIdx.x];
    __syncthreads();
    int t = blockIdx.x * 256 + threadIdx.x;
    int node = t >> 5;
    int o = t & 31;
    if (node >= n) return;
    float acc = cat_l[(size_t)node * 128 + o];
    const int k0 = rowptr[node], k1 = rowptr[node + 1];
    for (int k = k0; k < k1; k += 8) {
        unsigned int pp[8];
        unsigned int hh[8];
#pragma unroll
        for (int j = 0; j < 8; ++j) {
            int kk = k + j;
            pp[j] = epack[(kk < k1) ? kk : (k1 - 1)];
        }
#pragma unroll
        for (int j = 0; j < 8; ++j)
            hh[j] = hb2[(size_t)(pp[j] & SRC_MASK) * 32 + o];
#pragma unroll
        for (int j = 0; j < 8; ++j) {
            bool valid = (k + j) < k1;
            int et = (int)(pp[j] >> ETYPE_SHIFT);
            float w0 = valid ? c[et * 2 + 0] : 0.f;
            float w1 = valid ? c[et * 2 + 1] : 0.f;
            float h0 = __uint_as_float((hh[j] & 0xFFFFu) << 16);
            float h1 = __uint_as_float(hh[j] & 0xFFFF0000u);
            acc = fmaf(w0, h0, acc);
            acc = fmaf(w1, h1, acc);
        }
    }
    cat_l[(size_t)node * 128 + o] = tanhf(acc);
}

__global__ void k_head(const float* __restrict__ cat, const int* __restrict__ uidx,
                       const int* __restrict__ iidx, const float* __restrict__ w,
                       const float* __restrict__ b, float* __restrict__ out, int B) {
    int p = blockIdx.x;
    if (p >= B) return;
    int lane = threadIdx.x;  // 0..63
    const float* cu = cat + (size_t)uidx[p] * 128;
    const float* ci = cat + (size_t)iidx[p] * 128;
    float s = 0.f;
    s = fmaf(cu[lane], w[lane], s);
    s = fmaf(cu[lane + 64], w[lane + 64], s);
    s = fmaf(ci[lane], w[lane + 128], s);
    s = fmaf(ci[lane + 64], w[lane + 192], s);
    for (int d = 32; d > 0; d >>= 1) s += __shfl_down(s, d, 64);
    if (lane == 0) out[p] = 1.f / (1.f + expf(-(s + b[0])));
}

extern "C" void kernel_launch(void* const* d_in, const int* in_sizes, int n_in,
                              void* d_out, int out_size, void* d_ws, size_t ws_size,
                              hipStream_t stream) {
    const float* x      = (const float*)d_in[0];
    const int*   src    = (const int*)d_in[1];
    const int*   dst    = (const int*)d_in[2];
    const int*   etype  = (const int*)d_in[3];
    const int*   uidx   = (const int*)d_in[4];
    const int*   iidx   = (const int*)d_in[5];
    const float* lin1_w = (const float*)d_in[22];
    const float* lin1_b = (const float*)d_in[23];

    const int N = in_sizes[0] / 64;
    const int E = in_sizes[1];
    const int B = in_sizes[4];
    const int NBUK = (N + BUK_W - 1) >> BUK_SH;

    // workspace carve-out (256B aligned)
    char* p = (char*)d_ws;
    auto alloc = [&](size_t bytes) -> void* {
        void* r = (void*)p;
        p += (bytes + 255) & ~(size_t)255;
        return r;
    };
    unsigned int*       hb2     = (unsigned int*)alloc((size_t)N * 32 * sizeof(unsigned int));
    float*              cat     = (float*)alloc((size_t)N * 128 * sizeof(float));
    int*                rowptr  = (int*)alloc((size_t)(N + 1) * sizeof(int));
    unsigned int*       epack   = (unsigned int*)alloc((size_t)E * sizeof(unsigned int));
    unsigned long long* binned  = (unsigned long long*)alloc((size_t)E * sizeof(unsigned long long));
    int*                gBukCnt = (int*)alloc(1024 * sizeof(int));
    int*                gBukCur = (int*)alloc(1024 * sizeof(int));  // adjacent to gBukCnt
    int*                bukOff  = (int*)alloc(1025 * sizeof(int));

    // ---- CSR build (bucket pipeline) ----
    hipMemsetAsync(gBukCnt, 0, 2048 * sizeof(int), stream);  // gBukCnt + gBukCur
    int ebGrid = (E + 2047) / 2048;
    k_buk_count<<<ebGrid, 256, 0, stream>>>(dst, gBukCnt, E);
    k_buk_scan<<<1, 1024, 0, stream>>>(gBukCnt, bukOff, NBUK);
    k_binscatter<<<ebGrid, 256, 0, stream>>>(src, dst, etype, bukOff, gBukCur,
                                             binned, E, NBUK);
    k_bucket_finalize<<<NBUK, 256, 0, stream>>>(binned, bukOff, rowptr, epack, N, E);

    // ---- 4 RGCN layers ----
    int tr_grid = (N + 63) / 64;
    int node_grid = (N * 32 + 255) / 256;
    for (int l = 0; l < 4; ++l) {
        const float* xin   = (l == 0) ? x : (cat + (size_t)(l - 1) * 32);
        int in_stride      = (l == 0) ? 64 : 128;
        const float* basis = (const float*)d_in[6 + l * 4];
        const float* comp  = (const float*)d_in[7 + l * 4];
        const float* wself = (const float*)d_in[8 + l * 4];
        const float* bias  = (const float*)d_in[9 + l * 4];
        if (l == 0)
            k_transform2<64><<<tr_grid, 256, 0, stream>>>(xin, in_stride, basis, wself,
                                                          bias, hb2, cat + (size_t)l * 32, N);
        else
            k_transform2<32><<<tr_grid, 256, 0, stream>>>(xin, in_stride, basis, wself,
                                                          bias, hb2, cat + (size_t)l * 32, N);
        k_aggregate<<<node_grid, 256, 0, stream>>>(hb2, epack, rowptr, comp,
                                                   cat + (size_t)l * 32, N);
    }

    // ---- head ----
    k_head<<<B, 64, 0, stream>>>(cat, uidx, iidx, lin1_w, lin1_b, (float*)d_out, B);
}

// Round 6
// 315.506 us; speedup vs baseline: 3.6107x; 1.2264x over previous
//
#include <hip/hip_runtime.h>
#include <hip/hip_bf16.h>

// ---------------------------------------------------------------------------
// RGCN (basis decomposition) x4 layers + pair-scoring head.
//
// CSR build (bucket pipeline):
//   A  k_buk_count      : LDS histogram of dst>>9 (512-node buckets)
//   A2 k_buk_scan       : 1-block exclusive scan -> bukOff[0..NBUK]
//   B  k_binscatter     : per 2048-edge block: counting-sort into LDS by
//                         bucket, reserve global space, contiguous writeout
//   C  k_bucket_finalize: per bucket: node histogram + scan in LDS, writes
//                         rowptr coalesced, scatters epack into 16KB window
//
// Layers:
//   k_transform3 : MFMA (v_mfma_f32_16x16x32_bf16) mini-GEMM
//                  [64 nodes x DI] @ [DI x 96] (basis0|basis1|wself).
//                  bf16 LDS tiles with XOR-slot swizzle; 4 waves x 6 C-tiles.
//                  -> hb2 (bf16x2 packed) + self part (f32) into cat.
//   k_aggregate  : pull over in-edges, masked 8-wide software pipeline, tanh.
//   cat [N,128] f32 holds all four layer states (concat layout).
//   k_head       : one wave per pair, 256-dim dot + sigmoid.
// ---------------------------------------------------------------------------

#define ETYPE_SHIFT 28
#define SRC_MASK 0x0FFFFFFFu
#define BUK_SH 9
#define BUK_W 512

typedef __attribute__((ext_vector_type(8))) short bf16x8;
typedef __attribute__((ext_vector_type(4))) float f32x4;

__device__ inline unsigned int f2bf(float f) {
    unsigned int u = __float_as_uint(f);
    return (u + 0x7FFFu + ((u >> 16) & 1u)) >> 16;
}

// Exclusive scan in place of a[0..M), M%4==0, M/4 <= 256. 256-thread block.
__device__ inline void block_exscan(int* a, int M, int* wsum /*shared int[4]*/) {
    const int t = threadIdx.x;
    const int q = M >> 2;
    int s0 = 0, s1 = 0, s2 = 0, s3 = 0, s = 0;
    if (t < q) {
        s0 = a[4 * t]; s1 = a[4 * t + 1]; s2 = a[4 * t + 2]; s3 = a[4 * t + 3];
        s = s0 + s1 + s2 + s3;
    }
    int lane = t & 63, wid = t >> 6;
    int val = s;
    for (int d = 1; d < 64; d <<= 1) {
        int u = __shfl_up(val, d, 64);
        if (lane >= d) val += u;
    }
    if (lane == 63) wsum[wid] = val;
    __syncthreads();
    int woff = 0;
    for (int w = 0; w < wid; ++w) woff += wsum[w];
    val += woff;              // inclusive over block
    int base = val - s;       // exclusive base for this thread's 4 elems
    __syncthreads();
    if (t < q) {
        a[4 * t]     = base;
        a[4 * t + 1] = base + s0;
        a[4 * t + 2] = base + s0 + s1;
        a[4 * t + 3] = base + s0 + s1 + s2;
    }
    __syncthreads();
}

// ---- A: bucket histogram ----
__global__ __launch_bounds__(256) void k_buk_count(const int* __restrict__ dst,
                                                   int* __restrict__ gBukCnt, int E) {
    __shared__ int hist[1024];
    const int t = threadIdx.x;
    for (int f = t; f < 1024; f += 256) hist[f] = 0;
    __syncthreads();
    int e0 = blockIdx.x * 2048;
    for (int k = 0; k < 8; ++k) {
        int e = e0 + k * 256 + t;
        if (e < E) atomicAdd(&hist[dst[e] >> BUK_SH], 1);
    }
    __syncthreads();
    for (int f = t; f < 1024; f += 256) {
        int c = hist[f];
        if (c) atomicAdd(&gBukCnt[f], c);
    }
}

// ---- A2: scan bucket counts (1 block, 1024 threads; nb <= 1024) ----
__global__ void k_buk_scan(const int* __restrict__ gBukCnt, int* __restrict__ bukOff,
                           int nb) {
    __shared__ int lds[1024];
    int tid = threadIdx.x;
    int v = (tid < nb) ? gBukCnt[tid] : 0;
    lds[tid] = v;
    __syncthreads();
    for (int d = 1; d < 1024; d <<= 1) {
        int u = (tid >= d) ? lds[tid - d] : 0;
        __syncthreads();
        lds[tid] += u;
        __syncthreads();
    }
    if (tid < nb) bukOff[tid] = lds[tid] - v;       // exclusive
    if (tid == nb - 1) bukOff[nb] = lds[tid];       // total = E
}

// ---- B: block counting-sort by bucket + contiguous segment writeout ----
__global__ __launch_bounds__(256) void k_binscatter(
    const int* __restrict__ src, const int* __restrict__ dst,
    const int* __restrict__ etype, const int* __restrict__ bukOff,
    int* __restrict__ gBukCur, unsigned long long* __restrict__ binned,
    int E, int NBUK)
{
    __shared__ int hist[1024];
    __shared__ int offs[1024];
    __shared__ int cur[1024];
    __shared__ int gb[1024];
    __shared__ int wsum[4];
    __shared__ unsigned long long stage[2048];
    const int t = threadIdx.x;
    for (int f = t; f < 1024; f += 256) { hist[f] = 0; cur[f] = 0; }
    __syncthreads();

    const int e0 = blockIdx.x * 2048;
    const int cntTot = min(2048, E - e0);
    unsigned long long pk[8];
    int bk[8];
#pragma unroll
    for (int k = 0; k < 8; ++k) {
        int e = e0 + k * 256 + t;
        if (e < E) {
            int d = dst[e];
            bk[k] = d >> BUK_SH;
            pk[k] = ((unsigned long long)(unsigned int)d << 32)
                  | (unsigned int)(src[e] | (etype[e] << ETYPE_SHIFT));
            atomicAdd(&hist[bk[k]], 1);
        } else bk[k] = -1;
    }
    __syncthreads();
    for (int f = t; f < 1024; f += 256) offs[f] = hist[f];
    __syncthreads();
    block_exscan(offs, 1024, wsum);
#pragma unroll
    for (int k = 0; k < 8; ++k) {
        if (bk[k] >= 0) {
            int pos = offs[bk[k]] + atomicAdd(&cur[bk[k]], 1);
            stage[pos] = pk[k];
        }
    }
    // reserve global space per bucket (one atomic per non-empty bucket)
    for (int f = t; f < NBUK; f += 256) {
        int c = hist[f];
        if (c > 0) gb[f] = bukOff[f] + atomicAdd(&gBukCur[f], c);
    }
    __syncthreads();
    // contiguous per-bucket segments
    for (int k = t; k < cntTot; k += 256) {
        unsigned long long v = stage[k];
        int b = (int)((unsigned int)(v >> 32) >> BUK_SH);
        binned[(size_t)gb[b] + (size_t)(k - offs[b])] = v;
    }
}

// ---- C: per-bucket finalize: rowptr + epack (all writes in 16KB window) ----
__global__ __launch_bounds__(256) void k_bucket_finalize(
    const unsigned long long* __restrict__ binned, const int* __restrict__ bukOff,
    int* __restrict__ rowptr, unsigned int* __restrict__ epack, int N, int E)
{
    __shared__ int nhist[512];
    __shared__ int ncur[512];
    __shared__ int wsum[4];
    const int t = threadIdx.x;
    const int b = blockIdx.x;
    for (int f = t; f < 512; f += 256) { nhist[f] = 0; ncur[f] = 0; }
    __syncthreads();
    const int k0 = bukOff[b], k1 = bukOff[b + 1];
    for (int k = k0 + t; k < k1; k += 256)
        atomicAdd(&nhist[(int)((unsigned int)(binned[k] >> 32) & (BUK_W - 1))], 1);
    __syncthreads();
    block_exscan(nhist, 512, wsum);
    for (int f = t; f < 512; f += 256) {
        int node = (b << BUK_SH) + f;
        if (node < N) rowptr[node] = k0 + nhist[f];
    }
    if (b == 0 && t == 0) rowptr[N] = E;
    for (int k = k0 + t; k < k1; k += 256) {
        unsigned long long v = binned[k];
        int dl = (int)((unsigned int)(v >> 32) & (BUK_W - 1));
        int pos = k0 + nhist[dl] + atomicAdd(&ncur[dl], 1);
        epack[pos] = (unsigned int)v;
    }
}

// ---- MFMA transform ----
// Block: 256 threads = 4 waves, 64 nodes. Out cols 0..95 = b0(0..31) |
// b1(32..63) | wself(64..95). Wave w: nodes w*16..w*16+15, all 6 out-tiles.
// LDS: bf16 tiles, row-XOR-swizzled 16B slots for conflict-free b128 reads.
template<int DI>
__global__ __launch_bounds__(256) void k_transform3(
    const float* __restrict__ xin, int in_stride,
    const float* __restrict__ basis, const float* __restrict__ wself,
    const float* __restrict__ bias,
    unsigned int* __restrict__ hb2, float* __restrict__ selfout, int n)
{
    constexpr int ROWB = DI * 2;            // bytes per LDS row
    constexpr int SMASK = (ROWB / 16) - 1;  // 16B-slot mask: 7 (DI64) / 3 (DI32)
    constexpr int C4 = DI / 4;              // 4-elem chunks per row
    __shared__ unsigned short xs[64 * DI];
    __shared__ unsigned short bt[96 * DI];
    const int t = threadIdx.x;

    auto swz = [](int row, int byteInRow) -> int {
        int slot = (byteInRow >> 4) ^ ((row ^ (row >> 2)) & SMASK);
        return row * ROWB + (slot << 4) + (byteInRow & 15);
    };

    // ---- stage weights (transposed to [out][k], bf16, swizzled) ----
    for (int f = t; f < 96 * C4; f += 256) {
        int k4 = f / 96;                // chunk index (k = 4*k4)
        int o  = f - k4 * 96;           // out col 0..95 (fast -> coalesced)
        const float* sp = (o < 64) ? (basis + (size_t)(o >> 5) * DI * 32 + (o & 31))
                                   : (wself + (o - 64));
        int k = 4 * k4;
        ushort4 pv;
        pv.x = (unsigned short)f2bf(sp[(size_t)(k + 0) * 32]);
        pv.y = (unsigned short)f2bf(sp[(size_t)(k + 1) * 32]);
        pv.z = (unsigned short)f2bf(sp[(size_t)(k + 2) * 32]);
        pv.w = (unsigned short)f2bf(sp[(size_t)(k + 3) * 32]);
        *(ushort4*)((char*)bt + swz(o, k * 2)) = pv;
    }

    // ---- stage x tile (bf16, swizzled) ----
    const int node0 = blockIdx.x * 64;
    for (int f = t; f < 64 * C4; f += 256) {
        int nloc = f / C4, k4 = f - nloc * C4;
        int node = node0 + nloc;
        float4 v = make_float4(0.f, 0.f, 0.f, 0.f);
        if (node < n) v = *(const float4*)(xin + (size_t)node * in_stride + 4 * k4);
        ushort4 pv;
        pv.x = (unsigned short)f2bf(v.x);
        pv.y = (unsigned short)f2bf(v.y);
        pv.z = (unsigned short)f2bf(v.z);
        pv.w = (unsigned short)f2bf(v.w);
        *(ushort4*)((char*)xs + swz(nloc, 8 * k4)) = pv;
    }
    __syncthreads();

    const int w = t >> 6;          // wave 0..3
    const int l = t & 63;
    const int lr = l & 15;         // A row-in-tile / B out col / C col
    const int lg = l >> 4;         // k-group

    f32x4 c[6];
#pragma unroll
    for (int i = 0; i < 6; ++i) c[i] = (f32x4){0.f, 0.f, 0.f, 0.f};

#pragma unroll
    for (int ks = 0; ks < DI / 32; ++ks) {
        const int kb = ks * 64 + lg * 16;       // byte offset of this lane's 8 k's
        bf16x8 a = *(const bf16x8*)((char*)xs + swz(w * 16 + lr, kb));
#pragma unroll
        for (int tt = 0; tt < 6; ++tt) {
            bf16x8 b = *(const bf16x8*)((char*)bt + swz(tt * 16 + lr, kb));
            c[tt] = __builtin_amdgcn_mfma_f32_16x16x32_bf16(a, b, c[tt], 0, 0, 0);
        }
    }

    const float bia0 = bias[lr];
    const float bia1 = bias[16 + lr];
#pragma unroll
    for (int r = 0; r < 4; ++r) {
        int node = node0 + w * 16 + lg * 4 + r;
        if (node < n) {
            hb2[(size_t)node * 32 + lr]      = f2bf(c[0][r]) | (f2bf(c[2][r]) << 16);
            hb2[(size_t)node * 32 + 16 + lr] = f2bf(c[1][r]) | (f2bf(c[3][r]) << 16);
            selfout[(size_t)node * 128 + lr]      = c[4][r] + bia0;
            selfout[(size_t)node * 128 + 16 + lr] = c[5][r] + bia1;
        }
    }
}

// Pull aggregation + tanh. Masked 8-wide software pipeline: all 8 epack loads
// then all 8 hb2 gathers issued back-to-back (8 lines in flight per thread).
__global__ void k_aggregate(const unsigned int* __restrict__ hb2,
                            const unsigned int* __restrict__ epack,
                            const int* __restrict__ rowptr,
                            const float* __restrict__ comp,  // [8,2]
                            float* __restrict__ cat_l,       // cat + l*32, stride 128
                            int n) {
    __shared__ float c[16];
    if (threadIdx.x < 16) c[threadIdx.x] = comp[threadIdx.x];
    __syncthreads();
    int t = blockIdx.x * 256 + threadIdx.x;
    int node = t >> 5;
    int o = t & 31;
    if (node >= n) return;
    float acc = cat_l[(size_t)node * 128 + o];
    const int k0 = rowptr[node], k1 = rowptr[node + 1];
    for (int k = k0; k < k1; k += 8) {
        unsigned int pp[8];
        unsigned int hh[8];
#pragma unroll
        for (int j = 0; j < 8; ++j) {
            int kk = k + j;
            pp[j] = epack[(kk < k1) ? kk : (k1 - 1)];
        }
#pragma unroll
        for (int j = 0; j < 8; ++j)
            hh[j] = hb2[(size_t)(pp[j] & SRC_MASK) * 32 + o];
#pragma unroll
        for (int j = 0; j < 8; ++j) {
            bool valid = (k + j) < k1;
            int et = (int)(pp[j] >> ETYPE_SHIFT);
            float w0 = valid ? c[et * 2 + 0] : 0.f;
            float w1 = valid ? c[et * 2 + 1] : 0.f;
            float h0 = __uint_as_float((hh[j] & 0xFFFFu) << 16);
            float h1 = __uint_as_float(hh[j] & 0xFFFF0000u);
            acc = fmaf(w0, h0, acc);
            acc = fmaf(w1, h1, acc);
        }
    }
    cat_l[(size_t)node * 128 + o] = tanhf(acc);
}

__global__ void k_head(const float* __restrict__ cat, const int* __restrict__ uidx,
                       const int* __restrict__ iidx, const float* __restrict__ w,
                       const float* __restrict__ b, float* __restrict__ out, int B) {
    int p = blockIdx.x;
    if (p >= B) return;
    int lane = threadIdx.x;  // 0..63
    const float* cu = cat + (size_t)uidx[p] * 128;
    const float* ci = cat + (size_t)iidx[p] * 128;
    float s = 0.f;
    s = fmaf(cu[lane], w[lane], s);
    s = fmaf(cu[lane + 64], w[lane + 64], s);
    s = fmaf(ci[lane], w[lane + 128], s);
    s = fmaf(ci[lane + 64], w[lane + 192], s);
    for (int d = 32; d > 0; d >>= 1) s += __shfl_down(s, d, 64);
    if (lane == 0) out[p] = 1.f / (1.f + expf(-(s + b[0])));
}

extern "C" void kernel_launch(void* const* d_in, const int* in_sizes, int n_in,
                              void* d_out, int out_size, void* d_ws, size_t ws_size,
                              hipStream_t stream) {
    const float* x      = (const float*)d_in[0];
    const int*   src    = (const int*)d_in[1];
    const int*   dst    = (const int*)d_in[2];
    const int*   etype  = (const int*)d_in[3];
    const int*   uidx   = (const int*)d_in[4];
    const int*   iidx   = (const int*)d_in[5];
    const float* lin1_w = (const float*)d_in[22];
    const float* lin1_b = (const float*)d_in[23];

    const int N = in_sizes[0] / 64;
    const int E = in_sizes[1];
    const int B = in_sizes[4];
    const int NBUK = (N + BUK_W - 1) >> BUK_SH;

    // workspace carve-out (256B aligned)
    char* p = (char*)d_ws;
    auto alloc = [&](size_t bytes) -> void* {
        void* r = (void*)p;
        p += (bytes + 255) & ~(size_t)255;
        return r;
    };
    unsigned int*       hb2     = (unsigned int*)alloc((size_t)N * 32 * sizeof(unsigned int));
    float*              cat     = (float*)alloc((size_t)N * 128 * sizeof(float));
    int*                rowptr  = (int*)alloc((size_t)(N + 1) * sizeof(int));
    unsigned int*       epack   = (unsigned int*)alloc((size_t)E * sizeof(unsigned int));
    unsigned long long* binned  = (unsigned long long*)alloc((size_t)E * sizeof(unsigned long long));
    int*                gBukCnt = (int*)alloc(1024 * sizeof(int));
    int*                gBukCur = (int*)alloc(1024 * sizeof(int));  // adjacent to gBukCnt
    int*                bukOff  = (int*)alloc(1025 * sizeof(int));

    // ---- CSR build (bucket pipeline) ----
    hipMemsetAsync(gBukCnt, 0, 2048 * sizeof(int), stream);  // gBukCnt + gBukCur
    int ebGrid = (E + 2047) / 2048;
    k_buk_count<<<ebGrid, 256, 0, stream>>>(dst, gBukCnt, E);
    k_buk_scan<<<1, 1024, 0, stream>>>(gBukCnt, bukOff, NBUK);
    k_binscatter<<<ebGrid, 256, 0, stream>>>(src, dst, etype, bukOff, gBukCur,
                                             binned, E, NBUK);
    k_bucket_finalize<<<NBUK, 256, 0, stream>>>(binned, bukOff, rowptr, epack, N, E);

    // ---- 4 RGCN layers ----
    int tr_grid = (N + 63) / 64;
    int node_grid = (N * 32 + 255) / 256;
    for (int l = 0; l < 4; ++l) {
        const float* xin   = (l == 0) ? x : (cat + (size_t)(l - 1) * 32);
        int in_stride      = (l == 0) ? 64 : 128;
        const float* basis = (const float*)d_in[6 + l * 4];
        const float* comp  = (const float*)d_in[7 + l * 4];
        const float* wself = (const float*)d_in[8 + l * 4];
        const float* bias  = (const float*)d_in[9 + l * 4];
        if (l == 0)
            k_transform3<64><<<tr_grid, 256, 0, stream>>>(xin, in_stride, basis, wself,
                                                          bias, hb2, cat + (size_t)l * 32, N);
        else
            k_transform3<32><<<tr_grid, 256, 0, stream>>>(xin, in_stride, basis, wself,
                                                          bias, hb2, cat + (size_t)l * 32, N);
        k_aggregate<<<node_grid, 256, 0, stream>>>(hb2, epack, rowptr, comp,
                                                   cat + (size_t)l * 32, N);
    }

    // ---- head ----
    k_head<<<B, 64, 0, stream>>>(cat, uidx, iidx, lin1_w, lin1_b, (float*)d_out, B);
}

// Round 7
// 292.101 us; speedup vs baseline: 3.9000x; 1.0801x over previous
//
#include <hip/hip_runtime.h>
#include <hip/hip_bf16.h>

// ---------------------------------------------------------------------------
// RGCN (basis decomposition) x4 layers + pair-scoring head.
//
// CSR build (bucket pipeline):
//   A  k_buk_count      : LDS histogram of dst>>9 (512-node buckets)
//   A2 k_buk_scan       : 1-block exclusive scan -> bukOff[0..NBUK]
//   B  k_binscatter     : per 2048-edge block: counting-sort into LDS by
//                         bucket, reserve global space, contiguous writeout
//   C  k_bucket_finalize: per bucket: node histogram + scan in LDS, writes
//                         rowptr coalesced, scatters epack into 16KB window
//
// Layers:
//   k_transform3 : MFMA (v_mfma_f32_16x16x32_bf16) mini-GEMM
//                  [64 nodes x DI] @ [DI x 96] (basis0|basis1|wself).
//   k_aggregate  : pull over in-edges; 16 lanes/node x 2 outputs/lane,
//                  masked 8-wide software pipeline, 32-bit saddr offsets,
//                  packed-bf16 weight table; tanh in place.
//   cat [N,128] f32 holds all four layer states (concat layout).
//   k_head       : one wave per pair, 256-dim dot + sigmoid.
// ---------------------------------------------------------------------------

#define ETYPE_SHIFT 28
#define SRC_MASK 0x0FFFFFFFu
#define BUK_SH 9
#define BUK_W 512

typedef __attribute__((ext_vector_type(8))) short bf16x8;
typedef __attribute__((ext_vector_type(4))) float f32x4;

__device__ inline unsigned int f2bf(float f) {
    unsigned int u = __float_as_uint(f);
    return (u + 0x7FFFu + ((u >> 16) & 1u)) >> 16;
}

// Exclusive scan in place of a[0..M), M%4==0, M/4 <= 256. 256-thread block.
__device__ inline void block_exscan(int* a, int M, int* wsum /*shared int[4]*/) {
    const int t = threadIdx.x;
    const int q = M >> 2;
    int s0 = 0, s1 = 0, s2 = 0, s3 = 0, s = 0;
    if (t < q) {
        s0 = a[4 * t]; s1 = a[4 * t + 1]; s2 = a[4 * t + 2]; s3 = a[4 * t + 3];
        s = s0 + s1 + s2 + s3;
    }
    int lane = t & 63, wid = t >> 6;
    int val = s;
    for (int d = 1; d < 64; d <<= 1) {
        int u = __shfl_up(val, d, 64);
        if (lane >= d) val += u;
    }
    if (lane == 63) wsum[wid] = val;
    __syncthreads();
    int woff = 0;
    for (int w = 0; w < wid; ++w) woff += wsum[w];
    val += woff;              // inclusive over block
    int base = val - s;       // exclusive base for this thread's 4 elems
    __syncthreads();
    if (t < q) {
        a[4 * t]     = base;
        a[4 * t + 1] = base + s0;
        a[4 * t + 2] = base + s0 + s1;
        a[4 * t + 3] = base + s0 + s1 + s2;
    }
    __syncthreads();
}

// ---- A: bucket histogram ----
__global__ __launch_bounds__(256) void k_buk_count(const int* __restrict__ dst,
                                                   int* __restrict__ gBukCnt, int E) {
    __shared__ int hist[1024];
    const int t = threadIdx.x;
    for (int f = t; f < 1024; f += 256) hist[f] = 0;
    __syncthreads();
    int e0 = blockIdx.x * 2048;
    for (int k = 0; k < 8; ++k) {
        int e = e0 + k * 256 + t;
        if (e < E) atomicAdd(&hist[dst[e] >> BUK_SH], 1);
    }
    __syncthreads();
    for (int f = t; f < 1024; f += 256) {
        int c = hist[f];
        if (c) atomicAdd(&gBukCnt[f], c);
    }
}

// ---- A2: scan bucket counts (1 block, 1024 threads; nb <= 1024) ----
__global__ void k_buk_scan(const int* __restrict__ gBukCnt, int* __restrict__ bukOff,
                           int nb) {
    __shared__ int lds[1024];
    int tid = threadIdx.x;
    int v = (tid < nb) ? gBukCnt[tid] : 0;
    lds[tid] = v;
    __syncthreads();
    for (int d = 1; d < 1024; d <<= 1) {
        int u = (tid >= d) ? lds[tid - d] : 0;
        __syncthreads();
        lds[tid] += u;
        __syncthreads();
    }
    if (tid < nb) bukOff[tid] = lds[tid] - v;       // exclusive
    if (tid == nb - 1) bukOff[nb] = lds[tid];       // total = E
}

// ---- B: block counting-sort by bucket + contiguous segment writeout ----
__global__ __launch_bounds__(256) void k_binscatter(
    const int* __restrict__ src, const int* __restrict__ dst,
    const int* __restrict__ etype, const int* __restrict__ bukOff,
    int* __restrict__ gBukCur, unsigned long long* __restrict__ binned,
    int E, int NBUK)
{
    __shared__ int hist[1024];
    __shared__ int offs[1024];
    __shared__ int cur[1024];
    __shared__ int gb[1024];
    __shared__ int wsum[4];
    __shared__ unsigned long long stage[2048];
    const int t = threadIdx.x;
    for (int f = t; f < 1024; f += 256) { hist[f] = 0; cur[f] = 0; }
    __syncthreads();

    const int e0 = blockIdx.x * 2048;
    const int cntTot = min(2048, E - e0);
    unsigned long long pk[8];
    int bk[8];
#pragma unroll
    for (int k = 0; k < 8; ++k) {
        int e = e0 + k * 256 + t;
        if (e < E) {
            int d = dst[e];
            bk[k] = d >> BUK_SH;
            pk[k] = ((unsigned long long)(unsigned int)d << 32)
                  | (unsigned int)(src[e] | (etype[e] << ETYPE_SHIFT));
            atomicAdd(&hist[bk[k]], 1);
        } else bk[k] = -1;
    }
    __syncthreads();
    for (int f = t; f < 1024; f += 256) offs[f] = hist[f];
    __syncthreads();
    block_exscan(offs, 1024, wsum);
#pragma unroll
    for (int k = 0; k < 8; ++k) {
        if (bk[k] >= 0) {
            int pos = offs[bk[k]] + atomicAdd(&cur[bk[k]], 1);
            stage[pos] = pk[k];
        }
    }
    // reserve global space per bucket (one atomic per non-empty bucket)
    for (int f = t; f < NBUK; f += 256) {
        int c = hist[f];
        if (c > 0) gb[f] = bukOff[f] + atomicAdd(&gBukCur[f], c);
    }
    __syncthreads();
    // contiguous per-bucket segments
    for (int k = t; k < cntTot; k += 256) {
        unsigned long long v = stage[k];
        int b = (int)((unsigned int)(v >> 32) >> BUK_SH);
        binned[(size_t)gb[b] + (size_t)(k - offs[b])] = v;
    }
}

// ---- C: per-bucket finalize: rowptr + epack (all writes in 16KB window) ----
__global__ __launch_bounds__(256) void k_bucket_finalize(
    const unsigned long long* __restrict__ binned, const int* __restrict__ bukOff,
    int* __restrict__ rowptr, unsigned int* __restrict__ epack, int N, int E)
{
    __shared__ int nhist[512];
    __shared__ int ncur[512];
    __shared__ int wsum[4];
    const int t = threadIdx.x;
    const int b = blockIdx.x;
    for (int f = t; f < 512; f += 256) { nhist[f] = 0; ncur[f] = 0; }
    __syncthreads();
    const int k0 = bukOff[b], k1 = bukOff[b + 1];
    for (int k = k0 + t; k < k1; k += 256)
        atomicAdd(&nhist[(int)((unsigned int)(binned[k] >> 32) & (BUK_W - 1))], 1);
    __syncthreads();
    block_exscan(nhist, 512, wsum);
    for (int f = t; f < 512; f += 256) {
        int node = (b << BUK_SH) + f;
        if (node < N) rowptr[node] = k0 + nhist[f];
    }
    if (b == 0 && t == 0) rowptr[N] = E;
    for (int k = k0 + t; k < k1; k += 256) {
        unsigned long long v = binned[k];
        int dl = (int)((unsigned int)(v >> 32) & (BUK_W - 1));
        int pos = k0 + nhist[dl] + atomicAdd(&ncur[dl], 1);
        epack[pos] = (unsigned int)v;
    }
}

// ---- MFMA transform ----
// Block: 256 threads = 4 waves, 64 nodes. Out cols 0..95 = b0(0..31) |
// b1(32..63) | wself(64..95). Wave w: nodes w*16..w*16+15, all 6 out-tiles.
// LDS: bf16 tiles, row-XOR-swizzled 16B slots for conflict-free b128 reads.
template<int DI>
__global__ __launch_bounds__(256) void k_transform3(
    const float* __restrict__ xin, int in_stride,
    const float* __restrict__ basis, const float* __restrict__ wself,
    const float* __restrict__ bias,
    unsigned int* __restrict__ hb2, float* __restrict__ selfout, int n)
{
    constexpr int ROWB = DI * 2;            // bytes per LDS row
    constexpr int SMASK = (ROWB / 16) - 1;  // 16B-slot mask: 7 (DI64) / 3 (DI32)
    constexpr int C4 = DI / 4;              // 4-elem chunks per row
    __shared__ unsigned short xs[64 * DI];
    __shared__ unsigned short bt[96 * DI];
    const int t = threadIdx.x;

    auto swz = [](int row, int byteInRow) -> int {
        int slot = (byteInRow >> 4) ^ ((row ^ (row >> 2)) & SMASK);
        return row * ROWB + (slot << 4) + (byteInRow & 15);
    };

    // ---- stage weights (transposed to [out][k], bf16, swizzled) ----
    for (int f = t; f < 96 * C4; f += 256) {
        int k4 = f / 96;                // chunk index (k = 4*k4)
        int o  = f - k4 * 96;           // out col 0..95 (fast -> coalesced)
        const float* sp = (o < 64) ? (basis + (size_t)(o >> 5) * DI * 32 + (o & 31))
                                   : (wself + (o - 64));
        int k = 4 * k4;
        ushort4 pv;
        pv.x = (unsigned short)f2bf(sp[(size_t)(k + 0) * 32]);
        pv.y = (unsigned short)f2bf(sp[(size_t)(k + 1) * 32]);
        pv.z = (unsigned short)f2bf(sp[(size_t)(k + 2) * 32]);
        pv.w = (unsigned short)f2bf(sp[(size_t)(k + 3) * 32]);
        *(ushort4*)((char*)bt + swz(o, k * 2)) = pv;
    }

    // ---- stage x tile (bf16, swizzled) ----
    const int node0 = blockIdx.x * 64;
    for (int f = t; f < 64 * C4; f += 256) {
        int nloc = f / C4, k4 = f - nloc * C4;
        int node = node0 + nloc;
        float4 v = make_float4(0.f, 0.f, 0.f, 0.f);
        if (node < n) v = *(const float4*)(xin + (size_t)node * in_stride + 4 * k4);
        ushort4 pv;
        pv.x = (unsigned short)f2bf(v.x);
        pv.y = (unsigned short)f2bf(v.y);
        pv.z = (unsigned short)f2bf(v.z);
        pv.w = (unsigned short)f2bf(v.w);
        *(ushort4*)((char*)xs + swz(nloc, 8 * k4)) = pv;
    }
    __syncthreads();

    const int w = t >> 6;          // wave 0..3
    const int l = t & 63;
    const int lr = l & 15;         // A row-in-tile / B out col / C col
    const int lg = l >> 4;         // k-group

    f32x4 c[6];
#pragma unroll
    for (int i = 0; i < 6; ++i) c[i] = (f32x4){0.f, 0.f, 0.f, 0.f};

#pragma unroll
    for (int ks = 0; ks < DI / 32; ++ks) {
        const int kb = ks * 64 + lg * 16;       // byte offset of this lane's 8 k's
        bf16x8 a = *(const bf16x8*)((char*)xs + swz(w * 16 + lr, kb));
#pragma unroll
        for (int tt = 0; tt < 6; ++tt) {
            bf16x8 b = *(const bf16x8*)((char*)bt + swz(tt * 16 + lr, kb));
            c[tt] = __builtin_amdgcn_mfma_f32_16x16x32_bf16(a, b, c[tt], 0, 0, 0);
        }
    }

    const float bia0 = bias[lr];
    const float bia1 = bias[16 + lr];
#pragma unroll
    for (int r = 0; r < 4; ++r) {
        int node = node0 + w * 16 + lg * 4 + r;
        if (node < n) {
            hb2[(size_t)node * 32 + lr]      = f2bf(c[0][r]) | (f2bf(c[2][r]) << 16);
            hb2[(size_t)node * 32 + 16 + lr] = f2bf(c[1][r]) | (f2bf(c[3][r]) << 16);
            selfout[(size_t)node * 128 + lr]      = c[4][r] + bia0;
            selfout[(size_t)node * 128 + 16 + lr] = c[5][r] + bia1;
        }
    }
}

// Pull aggregation + tanh. 16 lanes/node, 2 outputs/lane (uint2 gather).
// Masked 8-wide software pipeline; 32-bit byte offsets (saddr form);
// packed-bf16 weight table in LDS (one broadcast read per edge).
__global__ __launch_bounds__(256) void k_aggregate(
    const unsigned int* __restrict__ hb2,
    const unsigned int* __restrict__ epack,
    const int* __restrict__ rowptr,
    const float* __restrict__ comp,  // [8,2]
    float* __restrict__ cat_l,       // cat + l*32, row stride 128
    int n)
{
    __shared__ unsigned int cw[8];   // packed bf16 weights (w0 lo | w1 hi)
    if (threadIdx.x < 8)
        cw[threadIdx.x] = f2bf(comp[threadIdx.x * 2 + 0])
                        | (f2bf(comp[threadIdx.x * 2 + 1]) << 16);
    __syncthreads();
    int t = blockIdx.x * 256 + threadIdx.x;
    int node = t >> 4;
    int oj = t & 15;                 // outputs 2*oj, 2*oj+1
    if (node >= n) return;
    float* cp = cat_l + (size_t)node * 128 + 2 * oj;
    float acc0 = cp[0];
    float acc1 = cp[1];
    const int k0 = rowptr[node], k1 = rowptr[node + 1];
    const unsigned gbase = (unsigned)oj * 8u;   // byte offset within hb2 row
    for (int k = k0; k < k1; k += 8) {
        unsigned int pp[8];
        uint2 hh[8];
#pragma unroll
        for (int j = 0; j < 8; ++j) {
            unsigned kk = (unsigned)min(k + j, k1 - 1);
            pp[j] = *(const unsigned int*)((const char*)epack + kk * 4u);
        }
#pragma unroll
        for (int j = 0; j < 8; ++j) {
            unsigned boff = (pp[j] & SRC_MASK) * 128u + gbase;
            hh[j] = *(const uint2*)((const char*)hb2 + boff);
        }
#pragma unroll
        for (int j = 0; j < 8; ++j) {
            bool valid = (k + j) < k1;
            unsigned w = cw[pp[j] >> ETYPE_SHIFT];
            unsigned hx = valid ? hh[j].x : 0u;
            unsigned hy = valid ? hh[j].y : 0u;
            float w0 = __uint_as_float(w << 16);
            float w1 = __uint_as_float(w & 0xFFFF0000u);
            acc0 = fmaf(w0, __uint_as_float(hx << 16), acc0);
            acc0 = fmaf(w1, __uint_as_float(hx & 0xFFFF0000u), acc0);
            acc1 = fmaf(w0, __uint_as_float(hy << 16), acc1);
            acc1 = fmaf(w1, __uint_as_float(hy & 0xFFFF0000u), acc1);
        }
    }
    float2 r;
    r.x = tanhf(acc0);
    r.y = tanhf(acc1);
    *(float2*)cp = r;
}

__global__ void k_head(const float* __restrict__ cat, const int* __restrict__ uidx,
                       const int* __restrict__ iidx, const float* __restrict__ w,
                       const float* __restrict__ b, float* __restrict__ out, int B) {
    int p = blockIdx.x;
    if (p >= B) return;
    int lane = threadIdx.x;  // 0..63
    const float* cu = cat + (size_t)uidx[p] * 128;
    const float* ci = cat + (size_t)iidx[p] * 128;
    float s = 0.f;
    s = fmaf(cu[lane], w[lane], s);
    s = fmaf(cu[lane + 64], w[lane + 64], s);
    s = fmaf(ci[lane], w[lane + 128], s);
    s = fmaf(ci[lane + 64], w[lane + 192], s);
    for (int d = 32; d > 0; d >>= 1) s += __shfl_down(s, d, 64);
    if (lane == 0) out[p] = 1.f / (1.f + expf(-(s + b[0])));
}

extern "C" void kernel_launch(void* const* d_in, const int* in_sizes, int n_in,
                              void* d_out, int out_size, void* d_ws, size_t ws_size,
                              hipStream_t stream) {
    const float* x      = (const float*)d_in[0];
    const int*   src    = (const int*)d_in[1];
    const int*   dst    = (const int*)d_in[2];
    const int*   etype  = (const int*)d_in[3];
    const int*   uidx   = (const int*)d_in[4];
    const int*   iidx   = (const int*)d_in[5];
    const float* lin1_w = (const float*)d_in[22];
    const float* lin1_b = (const float*)d_in[23];

    const int N = in_sizes[0] / 64;
    const int E = in_sizes[1];
    const int B = in_sizes[4];
    const int NBUK = (N + BUK_W - 1) >> BUK_SH;

    // workspace carve-out (256B aligned)
    char* p = (char*)d_ws;
    auto alloc = [&](size_t bytes) -> void* {
        void* r = (void*)p;
        p += (bytes + 255) & ~(size_t)255;
        return r;
    };
    unsigned int*       hb2     = (unsigned int*)alloc((size_t)N * 32 * sizeof(unsigned int));
    float*              cat     = (float*)alloc((size_t)N * 128 * sizeof(float));
    int*                rowptr  = (int*)alloc((size_t)(N + 1) * sizeof(int));
    unsigned int*       epack   = (unsigned int*)alloc((size_t)E * sizeof(unsigned int));
    unsigned long long* binned  = (unsigned long long*)alloc((size_t)E * sizeof(unsigned long long));
    int*                gBukCnt = (int*)alloc(1024 * sizeof(int));
    int*                gBukCur = (int*)alloc(1024 * sizeof(int));  // adjacent to gBukCnt
    int*                bukOff  = (int*)alloc(1025 * sizeof(int));

    // ---- CSR build (bucket pipeline) ----
    hipMemsetAsync(gBukCnt, 0, 2048 * sizeof(int), stream);  // gBukCnt + gBukCur
    int ebGrid = (E + 2047) / 2048;
    k_buk_count<<<ebGrid, 256, 0, stream>>>(dst, gBukCnt, E);
    k_buk_scan<<<1, 1024, 0, stream>>>(gBukCnt, bukOff, NBUK);
    k_binscatter<<<ebGrid, 256, 0, stream>>>(src, dst, etype, bukOff, gBukCur,
                                             binned, E, NBUK);
    k_bucket_finalize<<<NBUK, 256, 0, stream>>>(binned, bukOff, rowptr, epack, N, E);

    // ---- 4 RGCN layers ----
    int tr_grid = (N + 63) / 64;
    int agg_grid = (N * 16 + 255) / 256;
    for (int l = 0; l < 4; ++l) {
        const float* xin   = (l == 0) ? x : (cat + (size_t)(l - 1) * 32);
        int in_stride      = (l == 0) ? 64 : 128;
        const float* basis = (const float*)d_in[6 + l * 4];
        const float* comp  = (const float*)d_in[7 + l * 4];
        const float* wself = (const float*)d_in[8 + l * 4];
        const float* bias  = (const float*)d_in[9 + l * 4];
        if (l == 0)
            k_transform3<64><<<tr_grid, 256, 0, stream>>>(xin, in_stride, basis, wself,
                                                          bias, hb2, cat + (size_t)l * 32, N);
        else
            k_transform3<32><<<tr_grid, 256, 0, stream>>>(xin, in_stride, basis, wself,
                                                          bias, hb2, cat + (size_t)l * 32, N);
        k_aggregate<<<agg_grid, 256, 0, stream>>>(hb2, epack, rowptr, comp,
                                                  cat + (size_t)l * 32, N);
    }

    // ---- head ----
    k_head<<<B, 64, 0, stream>>>(cat, uidx, iidx, lin1_w, lin1_b, (float*)d_out, B);
}

// Round 8
// 291.646 us; speedup vs baseline: 3.9061x; 1.0016x over previous
//
#include <hip/hip_runtime.h>
#include <hip/hip_bf16.h>

// ---------------------------------------------------------------------------
// RGCN (basis decomposition) x4 layers + pair-scoring head.
//
// CSR build (bucket pipeline):
//   A  k_buk_count      : LDS histogram of dst>>9 (512-node buckets)
//   A2 k_buk_scan       : 1-block exclusive scan -> bukOff[0..NBUK]
//   B  k_binscatter     : per 2048-edge block: counting-sort into LDS by
//                         bucket, reserve global space, contiguous writeout.
//                         binned is u32: et[31:29] | dstLocal[28:20] | src[17:0]
//   C  k_bucket_finalize: per bucket: node histogram + scan in LDS, writes
//                         rowptr coalesced, scatters epack (et<<29|src) into
//                         a 16KB window
//
// Layers:
//   k_transform3 : MFMA (v_mfma_f32_16x16x32_bf16) mini-GEMM
//                  [64 nodes x DI] @ [DI x 96] (basis0|basis1|wself).
//   k_aggregate  : pull over in-edges; 8 lanes/node x 4 outputs/lane,
//                  masked 8-wide pipeline of uint4 gathers (2x bytes in
//                  flight vs R7), packed-bf16 weight table, fast tanh.
//   cat [N,128] f32 holds all four layer states (concat layout).
//   k_head       : one wave per pair, 256-dim dot + sigmoid.
// ---------------------------------------------------------------------------

#define SRC_MASK 0x3FFFFu
#define BUK_SH 9
#define BUK_W 512

typedef __attribute__((ext_vector_type(8))) short bf16x8;
typedef __attribute__((ext_vector_type(4))) float f32x4;

__device__ inline unsigned int f2bf(float f) {
    unsigned int u = __float_as_uint(f);
    return (u + 0x7FFFu + ((u >> 16) & 1u)) >> 16;
}

__device__ inline float fast_tanh(float x) {
    float xc = fminf(fmaxf(x, -15.f), 15.f);
    float e = __expf(2.f * xc);
    return (e - 1.f) * __builtin_amdgcn_rcpf(e + 1.f);
}

// Exclusive scan in place of a[0..M), M%4==0, M/4 <= 256. 256-thread block.
__device__ inline void block_exscan(int* a, int M, int* wsum /*shared int[4]*/) {
    const int t = threadIdx.x;
    const int q = M >> 2;
    int s0 = 0, s1 = 0, s2 = 0, s3 = 0, s = 0;
    if (t < q) {
        s0 = a[4 * t]; s1 = a[4 * t + 1]; s2 = a[4 * t + 2]; s3 = a[4 * t + 3];
        s = s0 + s1 + s2 + s3;
    }
    int lane = t & 63, wid = t >> 6;
    int val = s;
    for (int d = 1; d < 64; d <<= 1) {
        int u = __shfl_up(val, d, 64);
        if (lane >= d) val += u;
    }
    if (lane == 63) wsum[wid] = val;
    __syncthreads();
    int woff = 0;
    for (int w = 0; w < wid; ++w) woff += wsum[w];
    val += woff;              // inclusive over block
    int base = val - s;       // exclusive base for this thread's 4 elems
    __syncthreads();
    if (t < q) {
        a[4 * t]     = base;
        a[4 * t + 1] = base + s0;
        a[4 * t + 2] = base + s0 + s1;
        a[4 * t + 3] = base + s0 + s1 + s2;
    }
    __syncthreads();
}

// ---- A: bucket histogram ----
__global__ __launch_bounds__(256) void k_buk_count(const int* __restrict__ dst,
                                                   int* __restrict__ gBukCnt, int E) {
    __shared__ int hist[1024];
    const int t = threadIdx.x;
    for (int f = t; f < 1024; f += 256) hist[f] = 0;
    __syncthreads();
    int e0 = blockIdx.x * 2048;
    for (int k = 0; k < 8; ++k) {
        int e = e0 + k * 256 + t;
        if (e < E) atomicAdd(&hist[dst[e] >> BUK_SH], 1);
    }
    __syncthreads();
    for (int f = t; f < 1024; f += 256) {
        int c = hist[f];
        if (c) atomicAdd(&gBukCnt[f], c);
    }
}

// ---- A2: scan bucket counts (1 block, 1024 threads; nb <= 1024) ----
__global__ void k_buk_scan(const int* __restrict__ gBukCnt, int* __restrict__ bukOff,
                           int nb) {
    __shared__ int lds[1024];
    int tid = threadIdx.x;
    int v = (tid < nb) ? gBukCnt[tid] : 0;
    lds[tid] = v;
    __syncthreads();
    for (int d = 1; d < 1024; d <<= 1) {
        int u = (tid >= d) ? lds[tid - d] : 0;
        __syncthreads();
        lds[tid] += u;
        __syncthreads();
    }
    if (tid < nb) bukOff[tid] = lds[tid] - v;       // exclusive
    if (tid == nb - 1) bukOff[nb] = lds[tid];       // total = E
}

// ---- B: block counting-sort by bucket + contiguous segment writeout ----
__global__ __launch_bounds__(256) void k_binscatter(
    const int* __restrict__ src, const int* __restrict__ dst,
    const int* __restrict__ etype, const int* __restrict__ bukOff,
    int* __restrict__ gBukCur, unsigned int* __restrict__ binned,
    int E, int NBUK)
{
    __shared__ int hist[1024];
    __shared__ int offs[1024];
    __shared__ int cur[1024];
    __shared__ int gb[1024];
    __shared__ int wsum[4];
    __shared__ unsigned int stage[2048];
    __shared__ unsigned short stageB[2048];   // bucket of each staged position
    const int t = threadIdx.x;
    for (int f = t; f < 1024; f += 256) { hist[f] = 0; cur[f] = 0; }
    __syncthreads();

    const int e0 = blockIdx.x * 2048;
    const int cntTot = min(2048, E - e0);
    unsigned int pk[8];
    int bk[8];
#pragma unroll
    for (int k = 0; k < 8; ++k) {
        int e = e0 + k * 256 + t;
        if (e < E) {
            int d = dst[e];
            bk[k] = d >> BUK_SH;
            pk[k] = (unsigned int)src[e]
                  | ((unsigned int)etype[e] << 29)
                  | ((unsigned int)(d & (BUK_W - 1)) << 20);
            atomicAdd(&hist[bk[k]], 1);
        } else bk[k] = -1;
    }
    __syncthreads();
    for (int f = t; f < 1024; f += 256) offs[f] = hist[f];
    __syncthreads();
    block_exscan(offs, 1024, wsum);
#pragma unroll
    for (int k = 0; k < 8; ++k) {
        if (bk[k] >= 0) {
            int pos = offs[bk[k]] + atomicAdd(&cur[bk[k]], 1);
            stage[pos] = pk[k];
            stageB[pos] = (unsigned short)bk[k];
        }
    }
    // reserve global space per bucket (one atomic per non-empty bucket)
    for (int f = t; f < NBUK; f += 256) {
        int c = hist[f];
        if (c > 0) gb[f] = bukOff[f] + atomicAdd(&gBukCur[f], c);
    }
    __syncthreads();
    // contiguous per-bucket segments
    for (int k = t; k < cntTot; k += 256) {
        int b = stageB[k];
        binned[(size_t)gb[b] + (size_t)(k - offs[b])] = stage[k];
    }
}

// ---- C: per-bucket finalize: rowptr + epack (all writes in 16KB window) ----
__global__ __launch_bounds__(256) void k_bucket_finalize(
    const unsigned int* __restrict__ binned, const int* __restrict__ bukOff,
    int* __restrict__ rowptr, unsigned int* __restrict__ epack, int N, int E)
{
    __shared__ int nhist[512];
    __shared__ int ncur[512];
    __shared__ int wsum[4];
    const int t = threadIdx.x;
    const int b = blockIdx.x;
    for (int f = t; f < 512; f += 256) { nhist[f] = 0; ncur[f] = 0; }
    __syncthreads();
    const int k0 = bukOff[b], k1 = bukOff[b + 1];
    for (int k = k0 + t; k < k1; k += 256)
        atomicAdd(&nhist[(binned[k] >> 20) & (BUK_W - 1)], 1);
    __syncthreads();
    block_exscan(nhist, 512, wsum);
    for (int f = t; f < 512; f += 256) {
        int node = (b << BUK_SH) + f;
        if (node < N) rowptr[node] = k0 + nhist[f];
    }
    if (b == 0 && t == 0) rowptr[N] = E;
    for (int k = k0 + t; k < k1; k += 256) {
        unsigned int v = binned[k];
        int dl = (v >> 20) & (BUK_W - 1);
        int pos = k0 + nhist[dl] + atomicAdd(&ncur[dl], 1);
        epack[pos] = v & 0xE003FFFFu;   // et[31:29] | src[17:0]
    }
}

// ---- MFMA transform ----
// Block: 256 threads = 4 waves, 64 nodes. Out cols 0..95 = b0(0..31) |
// b1(32..63) | wself(64..95). Wave w: nodes w*16..w*16+15, all 6 out-tiles.
// LDS: bf16 tiles, row-XOR-swizzled 16B slots for conflict-free b128 reads.
template<int DI>
__global__ __launch_bounds__(256) void k_transform3(
    const float* __restrict__ xin, int in_stride,
    const float* __restrict__ basis, const float* __restrict__ wself,
    const float* __restrict__ bias,
    unsigned int* __restrict__ hb2, float* __restrict__ selfout, int n)
{
    constexpr int ROWB = DI * 2;            // bytes per LDS row
    constexpr int SMASK = (ROWB / 16) - 1;  // 16B-slot mask: 7 (DI64) / 3 (DI32)
    constexpr int C4 = DI / 4;              // 4-elem chunks per row
    __shared__ unsigned short xs[64 * DI];
    __shared__ unsigned short bt[96 * DI];
    const int t = threadIdx.x;

    auto swz = [](int row, int byteInRow) -> int {
        int slot = (byteInRow >> 4) ^ ((row ^ (row >> 2)) & SMASK);
        return row * ROWB + (slot << 4) + (byteInRow & 15);
    };

    // ---- stage weights (transposed to [out][k], bf16, swizzled) ----
    for (int f = t; f < 96 * C4; f += 256) {
        int k4 = f / 96;                // chunk index (k = 4*k4)
        int o  = f - k4 * 96;           // out col 0..95 (fast -> coalesced)
        const float* sp = (o < 64) ? (basis + (size_t)(o >> 5) * DI * 32 + (o & 31))
                                   : (wself + (o - 64));
        int k = 4 * k4;
        ushort4 pv;
        pv.x = (unsigned short)f2bf(sp[(size_t)(k + 0) * 32]);
        pv.y = (unsigned short)f2bf(sp[(size_t)(k + 1) * 32]);
        pv.z = (unsigned short)f2bf(sp[(size_t)(k + 2) * 32]);
        pv.w = (unsigned short)f2bf(sp[(size_t)(k + 3) * 32]);
        *(ushort4*)((char*)bt + swz(o, k * 2)) = pv;
    }

    // ---- stage x tile (bf16, swizzled) ----
    const int node0 = blockIdx.x * 64;
    for (int f = t; f < 64 * C4; f += 256) {
        int nloc = f / C4, k4 = f - nloc * C4;
        int node = node0 + nloc;
        float4 v = make_float4(0.f, 0.f, 0.f, 0.f);
        if (node < n) v = *(const float4*)(xin + (size_t)node * in_stride + 4 * k4);
        ushort4 pv;
        pv.x = (unsigned short)f2bf(v.x);
        pv.y = (unsigned short)f2bf(v.y);
        pv.z = (unsigned short)f2bf(v.z);
        pv.w = (unsigned short)f2bf(v.w);
        *(ushort4*)((char*)xs + swz(nloc, 8 * k4)) = pv;
    }
    __syncthreads();

    const int w = t >> 6;          // wave 0..3
    const int l = t & 63;
    const int lr = l & 15;         // A row-in-tile / B out col / C col
    const int lg = l >> 4;         // k-group

    f32x4 c[6];
#pragma unroll
    for (int i = 0; i < 6; ++i) c[i] = (f32x4){0.f, 0.f, 0.f, 0.f};

#pragma unroll
    for (int ks = 0; ks < DI / 32; ++ks) {
        const int kb = ks * 64 + lg * 16;       // byte offset of this lane's 8 k's
        bf16x8 a = *(const bf16x8*)((char*)xs + swz(w * 16 + lr, kb));
#pragma unroll
        for (int tt = 0; tt < 6; ++tt) {
            bf16x8 b = *(const bf16x8*)((char*)bt + swz(tt * 16 + lr, kb));
            c[tt] = __builtin_amdgcn_mfma_f32_16x16x32_bf16(a, b, c[tt], 0, 0, 0);
        }
    }

    const float bia0 = bias[lr];
    const float bia1 = bias[16 + lr];
#pragma unroll
    for (int r = 0; r < 4; ++r) {
        int node = node0 + w * 16 + lg * 4 + r;
        if (node < n) {
            hb2[(size_t)node * 32 + lr]      = f2bf(c[0][r]) | (f2bf(c[2][r]) << 16);
            hb2[(size_t)node * 32 + 16 + lr] = f2bf(c[1][r]) | (f2bf(c[3][r]) << 16);
            selfout[(size_t)node * 128 + lr]      = c[4][r] + bia0;
            selfout[(size_t)node * 128 + 16 + lr] = c[5][r] + bia1;
        }
    }
}

// Pull aggregation + tanh. 8 lanes/node, 4 outputs/lane (uint4 gather).
// Masked 8-wide pipeline: 8 x 16B gathers in flight per lane.
__global__ __launch_bounds__(256) void k_aggregate(
    const unsigned int* __restrict__ hb2,
    const unsigned int* __restrict__ epack,
    const int* __restrict__ rowptr,
    const float* __restrict__ comp,  // [8,2]
    float* __restrict__ cat_l,       // cat + l*32, row stride 128
    int n)
{
    __shared__ unsigned int cw[8];   // packed bf16 weights (w0 lo | w1 hi)
    if (threadIdx.x < 8)
        cw[threadIdx.x] = f2bf(comp[threadIdx.x * 2 + 0])
                        | (f2bf(comp[threadIdx.x * 2 + 1]) << 16);
    __syncthreads();
    int t = blockIdx.x * 256 + threadIdx.x;
    int node = t >> 3;
    int oj = t & 7;                  // outputs 4*oj .. 4*oj+3
    if (node >= n) return;
    float* cp = cat_l + (size_t)node * 128 + 4 * oj;
    float4 acc = *(float4*)cp;
    const int k0 = rowptr[node], k1 = rowptr[node + 1];
    const unsigned gbase = (unsigned)oj * 16u;   // byte offset within hb2 row
    for (int k = k0; k < k1; k += 8) {
        unsigned int pp[8];
        uint4 hh[8];
#pragma unroll
        for (int j = 0; j < 8; ++j)
            pp[j] = epack[min(k + j, k1 - 1)];
#pragma unroll
        for (int j = 0; j < 8; ++j) {
            unsigned boff = (pp[j] & SRC_MASK) * 128u + gbase;
            hh[j] = *(const uint4*)((const char*)hb2 + boff);
        }
#pragma unroll
        for (int j = 0; j < 8; ++j) {
            bool valid = (k + j) < k1;
            unsigned w = cw[pp[j] >> 29];
            float w0 = __uint_as_float(w << 16);
            float w1 = __uint_as_float(w & 0xFFFF0000u);
            unsigned hx = valid ? hh[j].x : 0u;
            unsigned hy = valid ? hh[j].y : 0u;
            unsigned hz = valid ? hh[j].z : 0u;
            unsigned hw = valid ? hh[j].w : 0u;
            acc.x = fmaf(w0, __uint_as_float(hx << 16), acc.x);
            acc.x = fmaf(w1, __uint_as_float(hx & 0xFFFF0000u), acc.x);
            acc.y = fmaf(w0, __uint_as_float(hy << 16), acc.y);
            acc.y = fmaf(w1, __uint_as_float(hy & 0xFFFF0000u), acc.y);
            acc.z = fmaf(w0, __uint_as_float(hz << 16), acc.z);
            acc.z = fmaf(w1, __uint_as_float(hz & 0xFFFF0000u), acc.z);
            acc.w = fmaf(w0, __uint_as_float(hw << 16), acc.w);
            acc.w = fmaf(w1, __uint_as_float(hw & 0xFFFF0000u), acc.w);
        }
    }
    float4 r;
    r.x = fast_tanh(acc.x);
    r.y = fast_tanh(acc.y);
    r.z = fast_tanh(acc.z);
    r.w = fast_tanh(acc.w);
    *(float4*)cp = r;
}

__global__ void k_head(const float* __restrict__ cat, const int* __restrict__ uidx,
                       const int* __restrict__ iidx, const float* __restrict__ w,
                       const float* __restrict__ b, float* __restrict__ out, int B) {
    int p = blockIdx.x;
    if (p >= B) return;
    int lane = threadIdx.x;  // 0..63
    const float* cu = cat + (size_t)uidx[p] * 128;
    const float* ci = cat + (size_t)iidx[p] * 128;
    float s = 0.f;
    s = fmaf(cu[lane], w[lane], s);
    s = fmaf(cu[lane + 64], w[lane + 64], s);
    s = fmaf(ci[lane], w[lane + 128], s);
    s = fmaf(ci[lane + 64], w[lane + 192], s);
    for (int d = 32; d > 0; d >>= 1) s += __shfl_down(s, d, 64);
    if (lane == 0) out[p] = 1.f / (1.f + expf(-(s + b[0])));
}

extern "C" void kernel_launch(void* const* d_in, const int* in_sizes, int n_in,
                              void* d_out, int out_size, void* d_ws, size_t ws_size,
                              hipStream_t stream) {
    const float* x      = (const float*)d_in[0];
    const int*   src    = (const int*)d_in[1];
    const int*   dst    = (const int*)d_in[2];
    const int*   etype  = (const int*)d_in[3];
    const int*   uidx   = (const int*)d_in[4];
    const int*   iidx   = (const int*)d_in[5];
    const float* lin1_w = (const float*)d_in[22];
    const float* lin1_b = (const float*)d_in[23];

    const int N = in_sizes[0] / 64;
    const int E = in_sizes[1];
    const int B = in_sizes[4];
    const int NBUK = (N + BUK_W - 1) >> BUK_SH;

    // workspace carve-out (256B aligned)
    char* p = (char*)d_ws;
    auto alloc = [&](size_t bytes) -> void* {
        void* r = (void*)p;
        p += (bytes + 255) & ~(size_t)255;
        return r;
    };
    unsigned int* hb2     = (unsigned int*)alloc((size_t)N * 32 * sizeof(unsigned int));
    float*        cat     = (float*)alloc((size_t)N * 128 * sizeof(float));
    int*          rowptr  = (int*)alloc((size_t)(N + 1) * sizeof(int));
    unsigned int* epack   = (unsigned int*)alloc((size_t)E * sizeof(unsigned int));
    unsigned int* binned  = (unsigned int*)alloc((size_t)E * sizeof(unsigned int));
    int*          gBukCnt = (int*)alloc(1024 * sizeof(int));
    int*          gBukCur = (int*)alloc(1024 * sizeof(int));  // adjacent to gBukCnt
    int*          bukOff  = (int*)alloc(1025 * sizeof(int));

    // ---- CSR build (bucket pipeline) ----
    hipMemsetAsync(gBukCnt, 0, 2048 * sizeof(int), stream);  // gBukCnt + gBukCur
    int ebGrid = (E + 2047) / 2048;
    k_buk_count<<<ebGrid, 256, 0, stream>>>(dst, gBukCnt, E);
    k_buk_scan<<<1, 1024, 0, stream>>>(gBukCnt, bukOff, NBUK);
    k_binscatter<<<ebGrid, 256, 0, stream>>>(src, dst, etype, bukOff, gBukCur,
                                             binned, E, NBUK);
    k_bucket_finalize<<<NBUK, 256, 0, stream>>>(binned, bukOff, rowptr, epack, N, E);

    // ---- 4 RGCN layers ----
    int tr_grid = (N + 63) / 64;
    int agg_grid = (N * 8 + 255) / 256;
    for (int l = 0; l < 4; ++l) {
        const float* xin   = (l == 0) ? x : (cat + (size_t)(l - 1) * 32);
        int in_stride      = (l == 0) ? 64 : 128;
        const float* basis = (const float*)d_in[6 + l * 4];
        const float* comp  = (const float*)d_in[7 + l * 4];
        const float* wself = (const float*)d_in[8 + l * 4];
        const float* bias  = (const float*)d_in[9 + l * 4];
        if (l == 0)
            k_transform3<64><<<tr_grid, 256, 0, stream>>>(xin, in_stride, basis, wself,
                                                          bias, hb2, cat + (size_t)l * 32, N);
        else
            k_transform3<32><<<tr_grid, 256, 0, stream>>>(xin, in_stride, basis, wself,
                                                          bias, hb2, cat + (size_t)l * 32, N);
        k_aggregate<<<agg_grid, 256, 0, stream>>>(hb2, epack, rowptr, comp,
                                                  cat + (size_t)l * 32, N);
    }

    // ---- head ----
    k_head<<<B, 64, 0, stream>>>(cat, uidx, iidx, lin1_w, lin1_b, (float*)d_out, B);
}